// Round 6
// baseline (296.529 us; speedup 1.0000x reference)
//
#include <hip/hip_runtime.h>
#include <hip/hip_bf16.h>

#define TSEQ 2048
#define CDIM 2048
#define NH   16
#define NKV  4
#define HDIM 128
#define BATCH 2
#define MROWS (BATCH*TSEQ)   // 4096
#define KVC   (NKV*HDIM)     // 512
#define QKVC  (CDIM + 2*KVC) // 3072: fused qkv row stride

typedef short bf16x8 __attribute__((ext_vector_type(8)));
typedef float f32x4  __attribute__((ext_vector_type(4)));

typedef const __attribute__((address_space(1))) void* gptr_t;
typedef __attribute__((address_space(3))) void* sptr_t;

__device__ inline void async16(const __hip_bfloat16* g, __hip_bfloat16* l) {
  __builtin_amdgcn_global_load_lds((gptr_t)g, (sptr_t)l, 16, 0, 0);
}

__device__ inline f32x4 mfma16(bf16x8 a, bf16x8 b, f32x4 c) {
  return __builtin_amdgcn_mfma_f32_16x16x32_bf16(a, b, c, 0, 0, 0);
}

__device__ inline float bfbits2f(unsigned short u) {
  return __uint_as_float(((unsigned)u) << 16);
}

__device__ inline unsigned short f2bfu(float x) {
  __hip_bfloat16 t = __float2bfloat16(x);
  return *(unsigned short*)&t;
}

// LDS XOR-swizzles: break row-stride bank aliasing for 16B fragment access.
__device__ inline int swz128(int row, int col) {  // rows of 128 bf16
  return row*128 + (((col >> 3) ^ (row & 15)) << 3) + (col & 7);
}
__device__ inline int swz64(int row, int col) {   // rows of 64 bf16
  return row*64 + ((((col >> 3) ^ row) & 7) << 3) + (col & 7);
}

// ---- dtype canary: inputs bf16 (flag=1) or f32 (flag=0) ----
__global__ void canary(const void* __restrict__ x, int* __restrict__ flag) {
  __shared__ int cnt[256];
  int tid = threadIdx.x;
  const unsigned short* u = (const unsigned short*)x;
  int c = 0;
#pragma unroll
  for (int i = 0; i < 4; ++i) {
    float a = fabsf(bfbits2f(u[(tid*4 + i)*2]));
    if (a >= 1e-6f && a <= 1e3f) c++;
  }
  cnt[tid] = c;
  __syncthreads();
  for (int s = 128; s > 0; s >>= 1) {
    if (tid < s) cnt[tid] += cnt[tid + s];
    __syncthreads();
  }
  if (tid == 0) *flag = (cnt[0] > 512) ? 1 : 0;
}

// ---- canonize ALL inputs in one launch; Wq/Wk/Wv land contiguously ----
__global__ __launch_bounds__(256) void canonize_all(
    const void* __restrict__ xs,  const void* __restrict__ wqs,
    const void* __restrict__ wks, const void* __restrict__ wvs,
    const void* __restrict__ wos, const void* __restrict__ gs,
    __hip_bfloat16* __restrict__ xd,   // [4096][2048]
    __hip_bfloat16* __restrict__ wqkv, // [3072][2048] (Wq;Wk;Wv rows)
    __hip_bfloat16* __restrict__ wod,  // [2048][2048]
    __hip_bfloat16* __restrict__ gd,   // [16]
    const int* __restrict__ flag)
{
  int blk = blockIdx.x;
  const void* src; __hip_bfloat16* dst; int base, n;
  if      (blk < 4096) { src = xs;  dst = xd;                base = blk;        n = MROWS*CDIM; }
  else if (blk < 6144) { src = wqs; dst = wqkv;              base = blk - 4096; n = CDIM*CDIM; }
  else if (blk < 6656) { src = wks; dst = wqkv + (size_t)CDIM*CDIM;            base = blk - 6144; n = KVC*CDIM; }
  else if (blk < 7168) { src = wvs; dst = wqkv + (size_t)(CDIM+KVC)*CDIM;      base = blk - 6656; n = KVC*CDIM; }
  else if (blk < 9216) { src = wos; dst = wod;               base = blk - 7168; n = CDIM*CDIM; }
  else                 { src = gs;  dst = gd;                base = 0;          n = NH; }
  int idx = base*2048 + threadIdx.x*8;
  if (idx >= n) return;
  if (*flag) {
    *(bf16x8*)&dst[idx] = *(const bf16x8*)((const __hip_bfloat16*)src + idx);
  } else {
    const float* s = (const float*)src + idx;
#pragma unroll
    for (int j = 0; j < 8; ++j) dst[idx + j] = __float2bfloat16(s[j]);
  }
}

// ---------------------------------------------------------------------------
// QKV GEMM: BM=256 x BN=192, BK=64. Grid 16x16 = 256 blocks = 1/CU.
// r6: cross-phase ds_read pipelining — each phase's fragments are read one
// phase EARLY, so MFMA clusters never wait on same-phase ds_read latency:
//  P1: ds a47(t),b2(t)      ; MFMA Q1(a03,b01)  ; lgkmcnt(0); barrier
//  P2: stage A(t+2)->buf    ; MFMA Q2(a47,b01)  ; barrier
//  P3: stage B(t+2)->buf    ; MFMA Q3(a03,b2)   ; vmcnt(7); barrier
//  P4: ds a03,b01 of t+1    ; MFMA Q4(a47,b2)   ; barrier
// Hazards: lgkmcnt(0)@P1-end => all waves' P1 reads of buf done before P2's
// stage writes buf. P4 preload reads buf^1 whose residency is certified by
// the P3 gate (vmcnt(7) leaves only A(t+2)+B(t+2) in flight). Preload reads
// are drained by the compiler's wait before next-P1's MFMAs, which precede
// the P1-end barrier that precedes the next stage into buf^1.
// ---------------------------------------------------------------------------
#define BK 64

__global__ __launch_bounds__(512, 2) void gemm_bt256(
    const __hip_bfloat16* __restrict__ A,
    const __hip_bfloat16* __restrict__ B,
    __hip_bfloat16* __restrict__ C,
    int M, int N, int K, int lda)
{
  __shared__ __align__(16) __hip_bfloat16 As[2][256*BK];  // 64 KiB
  __shared__ __align__(16) __hip_bfloat16 Bs[2][192*BK];  // 48 KiB
  const int tid  = threadIdx.x;
  const int wave = tid >> 6;
  const int lane = tid & 63;
  const int qd   = lane >> 4;
  const int ln   = lane & 15;
  const int m0   = blockIdx.y * 256;
  const int n0   = blockIdx.x * 192;
  const int wm   = (wave >> 2) * 128;  // 2 wave-rows
  const int wn   = (wave & 3) * 48;    // 4 wave-cols

  auto stageA = [&](int buf, int kt) {
    const __hip_bfloat16* src = A + (size_t)m0*lda + kt*BK;
    __hip_bfloat16* dst = &As[buf][0];
#pragma unroll
    for (int i = 0; i < 4; ++i) {
      int c = i*512 + tid;
      int row = c >> 3, sl = c & 7;
      int gs = sl ^ (row & 7);
      async16(&src[(size_t)row*lda + gs*8], &dst[(i*512 + wave*64)*8]);
    }
  };
  auto stageB = [&](int buf, int kt) {
    const __hip_bfloat16* src = B + (size_t)n0*K + kt*BK;
    __hip_bfloat16* dst = &Bs[buf][0];
#pragma unroll
    for (int i = 0; i < 3; ++i) {
      int c = i*512 + tid;
      int row = c >> 3, sl = c & 7;
      int gs = sl ^ (row & 7);
      async16(&src[(size_t)row*K + gs*8], &dst[(i*512 + wave*64)*8]);
    }
  };
  auto ldA = [&](int buf, int m, int kk) -> bf16x8 {
    int row = wm + m*16 + ln;
    return *(const bf16x8*)&As[buf][row*BK + (((kk*4 + qd) ^ (row & 7)) << 3)];
  };
  auto ldB = [&](int buf, int n, int kk) -> bf16x8 {
    int row = wn + n*16 + ln;
    return *(const bf16x8*)&Bs[buf][row*BK + (((kk*4 + qd) ^ (row & 7)) << 3)];
  };

  f32x4 acc[8][3] = {};
  const int nt = K / BK;

  stageA(0, 0); stageB(0, 0);
  if (nt > 1) {
    stageA(1, 1); stageB(1, 1);
    asm volatile("s_waitcnt vmcnt(7)" ::: "memory");
  } else {
    asm volatile("s_waitcnt vmcnt(0)" ::: "memory");
  }
  __builtin_amdgcn_s_barrier();

  bf16x8 a03[4][2], b01[2][2];
#pragma unroll
  for (int m = 0; m < 4; ++m)
#pragma unroll
    for (int kk = 0; kk < 2; ++kk) a03[m][kk] = ldA(0, m, kk);
#pragma unroll
  for (int n = 0; n < 2; ++n)
#pragma unroll
    for (int kk = 0; kk < 2; ++kk) b01[n][kk] = ldB(0, n, kk);

#pragma unroll 1
  for (int t = 0; t < nt; ++t) {
    const int buf = t & 1;
    bf16x8 a47[4][2], b2[2];

    // ---- P1: ds a47,b2 (used P2/P3); MFMA Q1 ----
#pragma unroll
    for (int m = 0; m < 4; ++m)
#pragma unroll
      for (int kk = 0; kk < 2; ++kk) a47[m][kk] = ldA(buf, 4 + m, kk);
#pragma unroll
    for (int kk = 0; kk < 2; ++kk) b2[kk] = ldB(buf, 2, kk);
    __builtin_amdgcn_s_setprio(1);
#pragma unroll
    for (int m = 0; m < 4; ++m)
#pragma unroll
      for (int n = 0; n < 2; ++n)
#pragma unroll
        for (int kk = 0; kk < 2; ++kk)
          acc[m][n] = mfma16(a03[m][kk], b01[n][kk], acc[m][n]);
    __builtin_amdgcn_s_setprio(0);
    asm volatile("s_waitcnt lgkmcnt(0)" ::: "memory");
    __builtin_amdgcn_s_barrier();

    // ---- P2: stage A(t+2); MFMA Q2 ----
    if (t + 2 < nt) stageA(buf, t + 2);
    __builtin_amdgcn_s_setprio(1);
#pragma unroll
    for (int m = 0; m < 4; ++m)
#pragma unroll
      for (int n = 0; n < 2; ++n)
#pragma unroll
        for (int kk = 0; kk < 2; ++kk)
          acc[4 + m][n] = mfma16(a47[m][kk], b01[n][kk], acc[4 + m][n]);
    __builtin_amdgcn_s_setprio(0);
    __builtin_amdgcn_s_barrier();

    // ---- P3: stage B(t+2); MFMA Q3; gate ----
    if (t + 2 < nt) stageB(buf, t + 2);
    __builtin_amdgcn_s_setprio(1);
#pragma unroll
    for (int m = 0; m < 4; ++m)
#pragma unroll
      for (int kk = 0; kk < 2; ++kk)
        acc[m][2] = mfma16(a03[m][kk], b2[kk], acc[m][2]);
    __builtin_amdgcn_s_setprio(0);
    if (t + 2 < nt) asm volatile("s_waitcnt vmcnt(7)" ::: "memory");
    else            asm volatile("s_waitcnt vmcnt(0)" ::: "memory");
    __builtin_amdgcn_s_barrier();

    // ---- P4: preload a03,b01 of t+1 (buf^1, resident); MFMA Q4 ----
    if (t + 1 < nt) {
#pragma unroll
      for (int m = 0; m < 4; ++m)
#pragma unroll
        for (int kk = 0; kk < 2; ++kk) a03[m][kk] = ldA(buf ^ 1, m, kk);
#pragma unroll
      for (int n = 0; n < 2; ++n)
#pragma unroll
        for (int kk = 0; kk < 2; ++kk) b01[n][kk] = ldB(buf ^ 1, n, kk);
    }
    __builtin_amdgcn_s_setprio(1);
#pragma unroll
    for (int m = 0; m < 4; ++m)
#pragma unroll
      for (int kk = 0; kk < 2; ++kk)
        acc[4 + m][2] = mfma16(a47[m][kk], b2[kk], acc[4 + m][2]);
    __builtin_amdgcn_s_setprio(0);
    __builtin_amdgcn_s_barrier();
  }

#pragma unroll
  for (int m = 0; m < 8; ++m)
#pragma unroll
    for (int n = 0; n < 3; ++n) {
      int row = m0 + wm + m*16 + qd*4;
      int col = n0 + wn + n*16 + ln;
#pragma unroll
      for (int r = 0; r < 4; ++r)
        C[(size_t)(row + r)*N + col] = __float2bfloat16(acc[m][n][r]);
    }
}

// ---------------------------------------------------------------------------
// Output GEMM: BM=256 x BN=128 (mirror of bt256; fixes the r5 BM=128
// regression). Grid 16x16 = 256 blocks = 1/CU. Same pipelined 4-phase
// structure; 6 loads/thread/tile -> gate vmcnt(6). Epilogue dtype per flag.
// ---------------------------------------------------------------------------
__global__ __launch_bounds__(512, 2) void gemm_out(
    const __hip_bfloat16* __restrict__ A,
    const __hip_bfloat16* __restrict__ B,
    void* __restrict__ C,
    int M, int N, int K, int lda, const int* __restrict__ flag)
{
  __shared__ __align__(16) __hip_bfloat16 As[2][256*BK];  // 64 KiB
  __shared__ __align__(16) __hip_bfloat16 Bs[2][128*BK];  // 32 KiB
  const int tid  = threadIdx.x;
  const int wave = tid >> 6;
  const int lane = tid & 63;
  const int qd   = lane >> 4;
  const int ln   = lane & 15;
  const int m0   = blockIdx.y * 256;
  const int n0   = blockIdx.x * 128;
  const int wm   = (wave >> 2) * 128;  // 2 wave-rows
  const int wn   = (wave & 3) * 32;    // 4 wave-cols

  auto stageA = [&](int buf, int kt) {
    const __hip_bfloat16* src = A + (size_t)m0*lda + kt*BK;
    __hip_bfloat16* dst = &As[buf][0];
#pragma unroll
    for (int i = 0; i < 4; ++i) {
      int c = i*512 + tid;
      int row = c >> 3, sl = c & 7;
      int gs = sl ^ (row & 7);
      async16(&src[(size_t)row*lda + gs*8], &dst[(i*512 + wave*64)*8]);
    }
  };
  auto stageB = [&](int buf, int kt) {
    const __hip_bfloat16* src = B + (size_t)n0*K + kt*BK;
    __hip_bfloat16* dst = &Bs[buf][0];
#pragma unroll
    for (int i = 0; i < 2; ++i) {
      int c = i*512 + tid;
      int row = c >> 3, sl = c & 7;
      int gs = sl ^ (row & 7);
      async16(&src[(size_t)row*K + gs*8], &dst[(i*512 + wave*64)*8]);
    }
  };
  auto ldA = [&](int buf, int m, int kk) -> bf16x8 {
    int row = wm + m*16 + ln;
    return *(const bf16x8*)&As[buf][row*BK + (((kk*4 + qd) ^ (row & 7)) << 3)];
  };
  auto ldB = [&](int buf, int n, int kk) -> bf16x8 {
    int row = wn + n*16 + ln;
    return *(const bf16x8*)&Bs[buf][row*BK + (((kk*4 + qd) ^ (row & 7)) << 3)];
  };

  f32x4 acc[8][2] = {};
  const int nt = K / BK;

  stageA(0, 0); stageB(0, 0);
  if (nt > 1) {
    stageA(1, 1); stageB(1, 1);
    asm volatile("s_waitcnt vmcnt(6)" ::: "memory");
  } else {
    asm volatile("s_waitcnt vmcnt(0)" ::: "memory");
  }
  __builtin_amdgcn_s_barrier();

  bf16x8 a03[4][2], bn0[2];
#pragma unroll
  for (int m = 0; m < 4; ++m)
#pragma unroll
    for (int kk = 0; kk < 2; ++kk) a03[m][kk] = ldA(0, m, kk);
#pragma unroll
  for (int kk = 0; kk < 2; ++kk) bn0[kk] = ldB(0, 0, kk);

#pragma unroll 1
  for (int t = 0; t < nt; ++t) {
    const int buf = t & 1;
    bf16x8 a47[4][2], bn1[2];

    // ---- P1: ds a47,bn1; MFMA Q1 (m0-3 x n0) ----
#pragma unroll
    for (int m = 0; m < 4; ++m)
#pragma unroll
      for (int kk = 0; kk < 2; ++kk) a47[m][kk] = ldA(buf, 4 + m, kk);
#pragma unroll
    for (int kk = 0; kk < 2; ++kk) bn1[kk] = ldB(buf, 1, kk);
    __builtin_amdgcn_s_setprio(1);
#pragma unroll
    for (int m = 0; m < 4; ++m)
#pragma unroll
      for (int kk = 0; kk < 2; ++kk)
        acc[m][0] = mfma16(a03[m][kk], bn0[kk], acc[m][0]);
    __builtin_amdgcn_s_setprio(0);
    asm volatile("s_waitcnt lgkmcnt(0)" ::: "memory");
    __builtin_amdgcn_s_barrier();

    // ---- P2: stage A(t+2); MFMA Q2 (m4-7 x n0) ----
    if (t + 2 < nt) stageA(buf, t + 2);
    __builtin_amdgcn_s_setprio(1);
#pragma unroll
    for (int m = 0; m < 4; ++m)
#pragma unroll
      for (int kk = 0; kk < 2; ++kk)
        acc[4 + m][0] = mfma16(a47[m][kk], bn0[kk], acc[4 + m][0]);
    __builtin_amdgcn_s_setprio(0);
    __builtin_amdgcn_s_barrier();

    // ---- P3: stage B(t+2); MFMA Q3 (m0-3 x n1); gate ----
    if (t + 2 < nt) stageB(buf, t + 2);
    __builtin_amdgcn_s_setprio(1);
#pragma unroll
    for (int m = 0; m < 4; ++m)
#pragma unroll
      for (int kk = 0; kk < 2; ++kk)
        acc[m][1] = mfma16(a03[m][kk], bn1[kk], acc[m][1]);
    __builtin_amdgcn_s_setprio(0);
    if (t + 2 < nt) asm volatile("s_waitcnt vmcnt(6)" ::: "memory");
    else            asm volatile("s_waitcnt vmcnt(0)" ::: "memory");
    __builtin_amdgcn_s_barrier();

    // ---- P4: preload a03,bn0 of t+1; MFMA Q4 (m4-7 x n1) ----
    if (t + 1 < nt) {
#pragma unroll
      for (int m = 0; m < 4; ++m)
#pragma unroll
        for (int kk = 0; kk < 2; ++kk) a03[m][kk] = ldA(buf ^ 1, m, kk);
#pragma unroll
      for (int kk = 0; kk < 2; ++kk) bn0[kk] = ldB(buf ^ 1, 0, kk);
    }
    __builtin_amdgcn_s_setprio(1);
#pragma unroll
    for (int m = 0; m < 4; ++m)
#pragma unroll
      for (int kk = 0; kk < 2; ++kk)
        acc[4 + m][1] = mfma16(a47[m][kk], bn1[kk], acc[4 + m][1]);
    __builtin_amdgcn_s_setprio(0);
    __builtin_amdgcn_s_barrier();
  }

  const bool isbf = (*flag != 0);
#pragma unroll
  for (int m = 0; m < 8; ++m)
#pragma unroll
    for (int n = 0; n < 2; ++n) {
      int row = m0 + wm + m*16 + qd*4;
      int col = n0 + wn + n*16 + ln;
#pragma unroll
      for (int r = 0; r < 4; ++r) {
        if (isbf) ((__hip_bfloat16*)C)[(size_t)(row + r)*N + col] = __float2bfloat16(acc[m][n][r]);
        else      ((float*)C)[(size_t)(row + r)*N + col] = acc[m][n][r];
      }
    }
}

// RMSNorm + RoPE + (gain/sqrt(HD) for q), in place on the fused qkv buffer.
__global__ __launch_bounds__(256) void prep_qk(
    __hip_bfloat16* __restrict__ qkv,  // [4096][3072]: q | k | v
    const __hip_bfloat16* __restrict__ gain)
{
  int wid  = blockIdx.x * 4 + (threadIdx.x >> 6);
  int lane = threadIdx.x & 63;
  bool isq = wid < MROWS*NH;
  int m, h;
  __hip_bfloat16* p;
  if (isq) { m = wid >> 4; h = wid & 15; p = qkv + (size_t)m*QKVC + h*HDIM; }
  else     { int w2 = wid - MROWS*NH; m = w2 >> 2; h = w2 & 3; p = qkv + (size_t)m*QKVC + CDIM + h*HDIM; }

  ushort2 raw = *(const ushort2*)((const unsigned short*)p + 2*lane);
  float e = bfbits2f(raw.x), o = bfbits2f(raw.y);
  float ss = e*e + o*o;
#pragma unroll
  for (int off = 32; off >= 1; off >>= 1) ss += __shfl_xor(ss, off);
  float rms = rsqrtf(ss * (1.0f/128.0f) + 1.1920928955078125e-07f);
  e *= rms; o *= rms;

  float theta = exp2f(-(float)(2*lane) * (1.0f/128.0f) * 13.287712379549449f);
  int t = m & (TSEQ-1);
  float fr = (float)t * theta;
  float c = cosf(fr), s = sinf(fr);
  float re = e*c - o*s;
  float ro = e*s + o*c;

  if (isq) {
    float g = bfbits2f(*(const unsigned short*)&gain[h]) * 0.08838834764831845f;
    re *= g; ro *= g;
  }
  p[2*lane]   = __float2bfloat16(re);
  p[2*lane+1] = __float2bfloat16(ro);
}

// v section of qkv [4096][3072] -> vt [B][NKV][HDIM][TSEQ]
__global__ __launch_bounds__(256) void transpose_v(
    const __hip_bfloat16* __restrict__ qkv, __hip_bfloat16* __restrict__ vt)
{
  __shared__ __hip_bfloat16 tile[32][34];
  int tx = threadIdx.x & 31;
  int ty = threadIdx.x >> 5;
  int r0 = blockIdx.x * 32;
  int c0 = blockIdx.y * 32;
#pragma unroll
  for (int i = 0; i < 4; ++i)
    tile[ty + i*8][tx] = qkv[(size_t)(r0 + ty + i*8)*QKVC + (CDIM + KVC) + c0 + tx];
  __syncthreads();
  int b = r0 >> 11;
  int t = r0 & (TSEQ-1);
  int hk = c0 >> 7;
  int d0 = c0 & (HDIM-1);
#pragma unroll
  for (int i = 0; i < 4; ++i) {
    int d = d0 + ty + i*8;
    vt[((size_t)((b*NKV + hk)*HDIM + d))*TSEQ + t + tx] = tile[tx][ty + i*8];
  }
}

// Flash attention v9: balanced pairs {p,31-p}, 4 waves, swapped-operand
// dataflow (verified r4/r5).
__global__ __launch_bounds__(256, 2) void attn_kernel(
    const __hip_bfloat16* __restrict__ qkv, // [B][T][3072] (read-only here)
    const __hip_bfloat16* __restrict__ vt,  // [B][NKV][HD][T]
    __hip_bfloat16* __restrict__ out)       // [B][T][2048] attn output
{
  const int tid  = threadIdx.x;
  const int wave = tid >> 6;   // 0..3
  const int lane = tid & 63;
  const int qd = lane >> 4, ln = lane & 15;
  const int p  = blockIdx.x;     // pair index 0..15 -> q-tiles {p, 31-p}
  const int h  = blockIdx.y;
  const int b  = blockIdx.z;
  const int hk = h >> 2;

  const __hip_bfloat16* K = qkv + (size_t)(b*TSEQ)*QKVC + CDIM + hk*HDIM;
  const __hip_bfloat16* V = vt + ((size_t)(b*NKV + hk)*HDIM)*TSEQ;

  __shared__ __align__(16) __hip_bfloat16 Ks[64*128];  // [t][d], swz128
  __shared__ __align__(16) __hip_bfloat16 Vs[128*64];  // [d][t], swz64
  __shared__ __align__(16) __hip_bfloat16 Pb[64*64];   // P^T as [q][kv], swz64
  __shared__ float Lb[4][64];                          // per-wave l partials

  auto issueK = [&](int t0) {
#pragma unroll
    for (int i = 0; i < 4; ++i) {
      int c = i*256 + tid;             // chunk; 16 chunks/row
      int row = c >> 4, cc = c & 15;
      int gcc = cc ^ (row & 15);
      async16(&K[(size_t)(t0 + row)*QKVC + gcc*8], &Ks[(i*256 + wave*64)*8]);
    }
  };
  auto issueV = [&](int t0) {
#pragma unroll
    for (int i = 0; i < 4; ++i) {
      int c = i*256 + tid;             // chunk; 8 chunks/row
      int row = c >> 3, cc = c & 7;
      int gcc = cc ^ (row & 7);
      async16(&V[(size_t)row*TSEQ + t0 + gcc*8], &Vs[(i*256 + wave*64)*8]);
    }
  };

#pragma unroll 1
  for (int seg = 0; seg < 2; ++seg) {
    const int qt = seg ? (31 - p) : p;
    const int q0 = qt * 64;

    // Q as B-operand fragments (col q = qsub*16+ln, k = kc*32+qd*8+e)
    bf16x8 qfr[4][4];
#pragma unroll
    for (int qsub = 0; qsub < 4; ++qsub)
#pragma unroll
      for (int kc = 0; kc < 4; ++kc)
        qfr[qsub][kc] = *(const bf16x8*)&qkv[((size_t)(b*TSEQ + q0 + qsub*16 + ln))*QKVC + h*HDIM + kc*32 + qd*8];

    // O^T accumulator: o[half][qsub] holds O^T[d = wave*32+half*16+qd*4+r][q = qsub*16+ln]
    f32x4 o[2][4] = {};
    float lacc[4] = {0.f, 0.f, 0.f, 0.f};

    __syncthreads();          // Ks free (prev segment epilogue readback done)
    issueK(0);
    __syncthreads();          // drain K[0]

#pragma unroll 1
    for (int kt = 0; kt <= qt; ++kt) {
      const int t0 = kt * 64;
      issueV(t0);             // Vs free since prev iter-end barrier

      // ---- QK^T swapped: S^T[kv][q], wave owns kv-rows wave*16..+15 ----
      f32x4 sc[4] = {};
#pragma unroll
      for (int kc = 0; kc < 4; ++kc) {
        bf16x8 kfa = *(const bf16x8*)&Ks[swz128(wave*16 + ln, kc*32 + qd*8)];
#pragma unroll
        for (int qsub = 0; qsub < 4; ++qsub)
          sc[qsub] = mfma16(kfa, qfr[qsub][kc], sc[qsub]);
      }
      if (kt == qt) {  // diagonal: causal mask (D: row=kv=qd*4+r, col=q=ln)
#pragma unroll
        for (int qsub = 0; qsub < 4; ++qsub)
#pragma unroll
          for (int r = 0; r < 4; ++r) {
            int kv = t0 + wave*16 + qd*4 + r;
            int q  = q0 + qsub*16 + ln;
            if (kv > q) sc[qsub][r] = -1.0e30f;
          }
      }
      // fixed-offset softmax: p = exp(s), defer l reduction
#pragma unroll
      for (int qsub = 0; qsub < 4; ++qsub) {
#pragma unroll
        for (int r = 0; r < 4; ++r)
          sc[qsub][r] = __expf(sc[qsub][r]);
        lacc[qsub] += (sc[qsub][0] + sc[qsub][1]) + (sc[qsub][2] + sc[qsub][3]);
      }

      // write P^T to Pb[q][kv] (8B packed, swz64; kv = wave*16+qd*4+r)
#pragma unroll
      for (int qsub = 0; qsub < 4; ++qsub) {
        ushort4 pk;
        pk.x = f2bfu(sc[qsub][0]); pk.y = f2bfu(sc[qsub][1]);
        pk.z = f2bfu(sc[qsub][2]); pk.w = f2bfu(sc[qsub][3]);
        *(ushort4*)&Pb[swz64(qsub*16 + ln, wave*16 + qd*4)] = pk;
      }

      __syncthreads();        // P visible; V[kt] drained; Ks consumed by all
      if (kt < qt) issueK(t0 + 64);   // overlaps PV

      // ---- PV d-split: O^T[d][q] += V^T[d][kv] * P^T[kv][q] ----
      __builtin_amdgcn_s_setprio(1);
#pragma unroll
      for (int kc2 = 0; kc2 < 2; ++kc2) {
        bf16x8 pfb[4];
#pragma unroll
        for (int qsub = 0; qsub < 4; ++qsub)
          pfb[qsub] = *(const bf16x8*)&Pb[swz64(qsub*16 + ln, kc2*32 + qd*8)];
#pragma unroll
        for (int half = 0; half < 2; ++half) {
          bf16x8 vfa = *(const bf16x8*)&Vs[swz64(wave*32 + half*16 + ln, kc2*32 + qd*8)];
#pragma unroll
          for (int qsub = 0; qsub < 4; ++qsub)
            o[half][qsub] = mfma16(vfa, pfb[qsub], o[half][qsub]);
        }
      }
      __builtin_amdgcn_s_setprio(0);
      __syncthreads();        // drain K[kt+1]; Vs & Pb free
    }

    // l: reduce across qd groups (kv within wave), then across waves via LDS
#pragma unroll
    for (int qsub = 0; qsub < 4; ++qsub) {
      lacc[qsub] += __shfl_xor(lacc[qsub], 16);
      lacc[qsub] += __shfl_xor(lacc[qsub], 32);
    }
    if (qd == 0) {
#pragma unroll
      for (int qsub = 0; qsub < 4; ++qsub)
        Lb[wave][qsub*16 + ln] = lacc[qsub];
    }
    __syncthreads();
    float inv[4];
#pragma unroll
    for (int qsub = 0; qsub < 4; ++qsub) {
      int q = qsub*16 + ln;
      inv[qsub] = 1.0f / (((Lb[0][q] + Lb[1][q]) + (Lb[2][q] + Lb[3][q])));
    }

    // epilogue: Obuf = Ks reuse, [q 64][d 128] swz128; wave writes its d-cols
#pragma unroll
    for (int half = 0; half < 2; ++half)
#pragma unroll
      for (int qsub = 0; qsub < 4; ++qsub) {
        ushort4 pk;
        pk.x = f2bfu(o[half][qsub][0] * inv[qsub]);
        pk.y = f2bfu(o[half][qsub][1] * inv[qsub]);
        pk.z = f2bfu(o[half][qsub][2] * inv[qsub]);
        pk.w = f2bfu(o[half][qsub][3] * inv[qsub]);
        *(ushort4*)&Ks[swz128(qsub*16 + ln, wave*32 + half*16 + qd*4)] = pk;
      }
    __syncthreads();          // writes visible before readback
#pragma unroll
    for (int pass = 0; pass < 4; ++pass) {
      int row = wave*16 + pass*4 + qd;
      bf16x8 val = *(const bf16x8*)&Ks[swz128(row, ln*8)];
      int q = q0 + row;
      *(bf16x8*)&out[((size_t)(b*TSEQ + q))*CDIM + h*HDIM + ln*8] = val;
    }
  }
}

extern "C" void kernel_launch(void* const* d_in, const int* in_sizes, int n_in,
                              void* d_out, int out_size, void* d_ws, size_t ws_size,
                              hipStream_t stream) {
  char* ws = (char*)d_ws;
  size_t off = 0;
  auto alloc = [&](size_t bytes) { char* p = ws + off; off += (bytes + 255) & ~(size_t)255; return p; };

  int* flag = (int*)alloc(256);
  __hip_bfloat16* xb   = (__hip_bfloat16*)alloc((size_t)MROWS*CDIM*2);   // 16.8 MB (x, then attn out)
  __hip_bfloat16* wqkv = (__hip_bfloat16*)alloc((size_t)QKVC*CDIM*2);    // 12.6 MB
  __hip_bfloat16* wob  = (__hip_bfloat16*)alloc((size_t)CDIM*CDIM*2);    //  8.4 MB
  __hip_bfloat16* gb   = (__hip_bfloat16*)alloc(256);
  __hip_bfloat16* qkv  = (__hip_bfloat16*)alloc((size_t)MROWS*QKVC*2);   // 25.2 MB
  __hip_bfloat16* vt   = (__hip_bfloat16*)alloc((size_t)MROWS*KVC*2);    //  4.2 MB

  canary<<<1, 256, 0, stream>>>(d_in[0], flag);

  canonize_all<<<9217, 256, 0, stream>>>(
      d_in[0], d_in[1], d_in[2], d_in[3], d_in[4], d_in[5],
      xb, wqkv, wob, gb, flag);

  // fused QKV projection: BM=256 x BN=192 -> grid 16x16 = 256 blocks = 1/CU.
  gemm_bt256<<<dim3(QKVC/192, MROWS/256), 512, 0, stream>>>(
      xb, wqkv, qkv, MROWS, QKVC, CDIM, CDIM);

  int nwaves = MROWS*NH + MROWS*NKV;
  prep_qk<<<nwaves/4, 256, 0, stream>>>(qkv, gb);

  transpose_v<<<dim3(MROWS/32, KVC/32), 256, 0, stream>>>(qkv, vt);

  // attention: balanced pairs {p, 31-p}, 256-thread blocks, swapped-operand
  attn_kernel<<<dim3(16, NH, BATCH), 256, 0, stream>>>(qkv, vt, xb);

  // output projection: BM=256 x BN=128 -> grid 16x16 = 256 blocks = 1/CU.
  gemm_out<<<dim3(CDIM/128, MROWS/256), 512, 0, stream>>>(
      xb, wob, d_out, MROWS, CDIM, CDIM, CDIM, flag);
}

// Round 7
// 292.751 us; speedup vs baseline: 1.0129x; 1.0129x over previous
//
#include <hip/hip_runtime.h>
#include <hip/hip_bf16.h>

#define TSEQ 2048
#define CDIM 2048
#define NH   16
#define NKV  4
#define HDIM 128
#define BATCH 2
#define MROWS (BATCH*TSEQ)   // 4096
#define KVC   (NKV*HDIM)     // 512
#define QKVC  (CDIM + 2*KVC) // 3072: fused qkv row stride

typedef short bf16x8 __attribute__((ext_vector_type(8)));
typedef float f32x4  __attribute__((ext_vector_type(4)));

typedef const __attribute__((address_space(1))) void* gptr_t;
typedef __attribute__((address_space(3))) void* sptr_t;

__device__ inline void async16(const __hip_bfloat16* g, __hip_bfloat16* l) {
  __builtin_amdgcn_global_load_lds((gptr_t)g, (sptr_t)l, 16, 0, 0);
}

__device__ inline f32x4 mfma16(bf16x8 a, bf16x8 b, f32x4 c) {
  return __builtin_amdgcn_mfma_f32_16x16x32_bf16(a, b, c, 0, 0, 0);
}

__device__ inline float bfbits2f(unsigned short u) {
  return __uint_as_float(((unsigned)u) << 16);
}

__device__ inline unsigned short f2bfu(float x) {
  __hip_bfloat16 t = __float2bfloat16(x);
  return *(unsigned short*)&t;
}

// LDS XOR-swizzles: break row-stride bank aliasing for 16B fragment access.
__device__ inline int swz128(int row, int col) {  // rows of 128 bf16
  return row*128 + (((col >> 3) ^ (row & 15)) << 3) + (col & 7);
}
__device__ inline int swz64(int row, int col) {   // rows of 64 bf16
  return row*64 + ((((col >> 3) ^ row) & 7) << 3) + (col & 7);
}

// ---- dtype canary: inputs bf16 (flag=1) or f32 (flag=0) ----
__global__ void canary(const void* __restrict__ x, int* __restrict__ flag) {
  __shared__ int cnt[256];
  int tid = threadIdx.x;
  const unsigned short* u = (const unsigned short*)x;
  int c = 0;
#pragma unroll
  for (int i = 0; i < 4; ++i) {
    float a = fabsf(bfbits2f(u[(tid*4 + i)*2]));
    if (a >= 1e-6f && a <= 1e3f) c++;
  }
  cnt[tid] = c;
  __syncthreads();
  for (int s = 128; s > 0; s >>= 1) {
    if (tid < s) cnt[tid] += cnt[tid + s];
    __syncthreads();
  }
  if (tid == 0) *flag = (cnt[0] > 512) ? 1 : 0;
}

// ---- canonize ALL inputs in one launch; Wq/Wk/Wv land contiguously ----
// r7: f32 path vectorized (2x float4 load + one 16B store). Same per-element
// conversion and order -> bit-identical output to the scalar version.
__global__ __launch_bounds__(256) void canonize_all(
    const void* __restrict__ xs,  const void* __restrict__ wqs,
    const void* __restrict__ wks, const void* __restrict__ wvs,
    const void* __restrict__ wos, const void* __restrict__ gs,
    __hip_bfloat16* __restrict__ xd,   // [4096][2048]
    __hip_bfloat16* __restrict__ wqkv, // [3072][2048] (Wq;Wk;Wv rows)
    __hip_bfloat16* __restrict__ wod,  // [2048][2048]
    __hip_bfloat16* __restrict__ gd,   // [16]
    const int* __restrict__ flag)
{
  int blk = blockIdx.x;
  const void* src; __hip_bfloat16* dst; int base, n;
  if      (blk < 4096) { src = xs;  dst = xd;                base = blk;        n = MROWS*CDIM; }
  else if (blk < 6144) { src = wqs; dst = wqkv;              base = blk - 4096; n = CDIM*CDIM; }
  else if (blk < 6656) { src = wks; dst = wqkv + (size_t)CDIM*CDIM;            base = blk - 6144; n = KVC*CDIM; }
  else if (blk < 7168) { src = wvs; dst = wqkv + (size_t)(CDIM+KVC)*CDIM;      base = blk - 6656; n = KVC*CDIM; }
  else if (blk < 9216) { src = wos; dst = wod;               base = blk - 7168; n = CDIM*CDIM; }
  else                 { src = gs;  dst = gd;                base = 0;          n = NH; }
  int idx = base*2048 + threadIdx.x*8;
  if (idx >= n) return;
  if (*flag) {
    *(bf16x8*)&dst[idx] = *(const bf16x8*)((const __hip_bfloat16*)src + idx);
  } else {
    const float* s = (const float*)src + idx;
    float4 f0 = *(const float4*)s;
    float4 f1 = *(const float4*)(s + 4);
    union { bf16x8 v; unsigned short u[8]; } o;
    o.u[0] = f2bfu(f0.x); o.u[1] = f2bfu(f0.y);
    o.u[2] = f2bfu(f0.z); o.u[3] = f2bfu(f0.w);
    o.u[4] = f2bfu(f1.x); o.u[5] = f2bfu(f1.y);
    o.u[6] = f2bfu(f1.z); o.u[7] = f2bfu(f1.w);
    *(bf16x8*)&dst[idx] = o.v;
  }
}

// ---------------------------------------------------------------------------
// QKV GEMM: BM=256 x BN=192, BK=64. Grid 16x16 = 256 blocks = 1/CU.
// r5 structure (best measured: 62.6 us / ~823 TF, bank-conflict 0):
//  P1: ds a03,b01 ; MFMA Q1 ; barrier
//  P2: ds a47     ; MFMA Q2 ; barrier
//  P3: ds b2 + stage A(t+2) ; MFMA Q3 ; barrier
//  P4: stage B(t+2) ; MFMA Q4 ; vmcnt(7) gate ; barrier
// ---------------------------------------------------------------------------
#define BK 64

__global__ __launch_bounds__(512, 2) void gemm_bt256(
    const __hip_bfloat16* __restrict__ A,
    const __hip_bfloat16* __restrict__ B,
    __hip_bfloat16* __restrict__ C,
    int M, int N, int K, int lda)
{
  __shared__ __align__(16) __hip_bfloat16 As[2][256*BK];  // 64 KiB
  __shared__ __align__(16) __hip_bfloat16 Bs[2][192*BK];  // 48 KiB
  const int tid  = threadIdx.x;
  const int wave = tid >> 6;
  const int lane = tid & 63;
  const int qd   = lane >> 4;
  const int ln   = lane & 15;
  const int m0   = blockIdx.y * 256;
  const int n0   = blockIdx.x * 192;
  const int wm   = (wave >> 2) * 128;  // 2 wave-rows
  const int wn   = (wave & 3) * 48;    // 4 wave-cols

  auto stageA = [&](int buf, int kt) {
    const __hip_bfloat16* src = A + (size_t)m0*lda + kt*BK;
    __hip_bfloat16* dst = &As[buf][0];
#pragma unroll
    for (int i = 0; i < 4; ++i) {
      int c = i*512 + tid;
      int row = c >> 3, sl = c & 7;
      int gs = sl ^ (row & 7);
      async16(&src[(size_t)row*lda + gs*8], &dst[(i*512 + wave*64)*8]);
    }
  };
  auto stageB = [&](int buf, int kt) {
    const __hip_bfloat16* src = B + (size_t)n0*K + kt*BK;
    __hip_bfloat16* dst = &Bs[buf][0];
#pragma unroll
    for (int i = 0; i < 3; ++i) {
      int c = i*512 + tid;
      int row = c >> 3, sl = c & 7;
      int gs = sl ^ (row & 7);
      async16(&src[(size_t)row*K + gs*8], &dst[(i*512 + wave*64)*8]);
    }
  };
  auto ldA = [&](int buf, int m, int kk) -> bf16x8 {
    int row = wm + m*16 + ln;
    return *(const bf16x8*)&As[buf][row*BK + (((kk*4 + qd) ^ (row & 7)) << 3)];
  };
  auto ldB = [&](int buf, int n, int kk) -> bf16x8 {
    int row = wn + n*16 + ln;
    return *(const bf16x8*)&Bs[buf][row*BK + (((kk*4 + qd) ^ (row & 7)) << 3)];
  };

  f32x4 acc[8][3] = {};
  const int nt = K / BK;

  stageA(0, 0); stageB(0, 0);
  if (nt > 1) {
    stageA(1, 1); stageB(1, 1);
    asm volatile("s_waitcnt vmcnt(7)" ::: "memory");
  } else {
    asm volatile("s_waitcnt vmcnt(0)" ::: "memory");
  }
  __builtin_amdgcn_s_barrier();

#pragma unroll 1
  for (int t = 0; t < nt; ++t) {
    const int buf = t & 1;
    bf16x8 a03[4][2], a47[4][2], b01[2][2], b2[2];

    // ---- P1: ds a03 + b01; MFMA Q1 ----
#pragma unroll
    for (int m = 0; m < 4; ++m)
#pragma unroll
      for (int kk = 0; kk < 2; ++kk) a03[m][kk] = ldA(buf, m, kk);
#pragma unroll
    for (int n = 0; n < 2; ++n)
#pragma unroll
      for (int kk = 0; kk < 2; ++kk) b01[n][kk] = ldB(buf, n, kk);
    __builtin_amdgcn_s_setprio(1);
#pragma unroll
    for (int m = 0; m < 4; ++m)
#pragma unroll
      for (int n = 0; n < 2; ++n)
#pragma unroll
        for (int kk = 0; kk < 2; ++kk)
          acc[m][n] = mfma16(a03[m][kk], b01[n][kk], acc[m][n]);
    __builtin_amdgcn_s_setprio(0);
    __builtin_amdgcn_s_barrier();

    // ---- P2: ds a47; MFMA Q2 ----
#pragma unroll
    for (int m = 0; m < 4; ++m)
#pragma unroll
      for (int kk = 0; kk < 2; ++kk) a47[m][kk] = ldA(buf, 4 + m, kk);
    __builtin_amdgcn_s_setprio(1);
#pragma unroll
    for (int m = 0; m < 4; ++m)
#pragma unroll
      for (int n = 0; n < 2; ++n)
#pragma unroll
        for (int kk = 0; kk < 2; ++kk)
          acc[4 + m][n] = mfma16(a47[m][kk], b01[n][kk], acc[4 + m][n]);
    __builtin_amdgcn_s_setprio(0);
    __builtin_amdgcn_s_barrier();

    // ---- P3: ds b2; stage A(t+2); MFMA Q3 ----
#pragma unroll
    for (int kk = 0; kk < 2; ++kk) b2[kk] = ldB(buf, 2, kk);
    if (t + 2 < nt) stageA(buf, t + 2);
    __builtin_amdgcn_s_setprio(1);
#pragma unroll
    for (int m = 0; m < 4; ++m)
#pragma unroll
      for (int kk = 0; kk < 2; ++kk)
        acc[m][2] = mfma16(a03[m][kk], b2[kk], acc[m][2]);
    __builtin_amdgcn_s_setprio(0);
    __builtin_amdgcn_s_barrier();

    // ---- P4: stage B(t+2); MFMA Q4; gate ----
    if (t + 2 < nt) stageB(buf, t + 2);
    __builtin_amdgcn_s_setprio(1);
#pragma unroll
    for (int m = 0; m < 4; ++m)
#pragma unroll
      for (int kk = 0; kk < 2; ++kk)
        acc[4 + m][2] = mfma16(a47[m][kk], b2[kk], acc[4 + m][2]);
    __builtin_amdgcn_s_setprio(0);
    if (t + 2 < nt) asm volatile("s_waitcnt vmcnt(7)" ::: "memory");
    else            asm volatile("s_waitcnt vmcnt(0)" ::: "memory");
    __builtin_amdgcn_s_barrier();
  }

#pragma unroll
  for (int m = 0; m < 8; ++m)
#pragma unroll
    for (int n = 0; n < 3; ++n) {
      int row = m0 + wm + m*16 + qd*4;
      int col = n0 + wn + n*16 + ln;
#pragma unroll
      for (int r = 0; r < 4; ++r)
        C[(size_t)(row + r)*N + col] = __float2bfloat16(acc[m][n][r]);
    }
}

// ---------------------------------------------------------------------------
// Output GEMM: r0-verified 128x128 BK=32 structure (2-barrier, 2 blocks/CU,
// 512 balanced blocks). Reverted: the r5/r6 1-block/CU 4-phase variants were
// ~8 us slower (totals arithmetic r4->r6). Epilogue dtype per flag.
// ---------------------------------------------------------------------------
__global__ __launch_bounds__(256, 2) void gemm_out(
    const __hip_bfloat16* __restrict__ A,
    const __hip_bfloat16* __restrict__ B,
    void* __restrict__ C,
    int M, int N, int K, int lda, const int* __restrict__ flag)
{
  __shared__ __align__(16) __hip_bfloat16 As[128*32];
  __shared__ __align__(16) __hip_bfloat16 Bs[128*32];
  const int tid  = threadIdx.x;
  const int wave = tid >> 6;
  const int lane = tid & 63;
  const int qd   = lane >> 4;
  const int ln   = lane & 15;
  const int m0   = blockIdx.y * 128;
  const int n0   = blockIdx.x * 128;
  const int wm   = (wave >> 1) * 64;
  const int wn   = (wave & 1) * 64;

  f32x4 acc[4][4] = {};

  for (int k0 = 0; k0 < K; k0 += 32) {
    __syncthreads();
#pragma unroll
    for (int r = 0; r < 2; ++r) {
      int e   = (r*256 + tid) * 8;
      int row = e >> 5;
      int col = e & 31;
      async16(&A[(size_t)(m0+row)*lda + k0 + col], &As[(size_t)(r*256 + wave*64)*8]);
      async16(&B[(size_t)(n0+row)*K   + k0 + col], &Bs[(size_t)(r*256 + wave*64)*8]);
    }
    __syncthreads();
    bf16x8 af[4], bfr[4];
#pragma unroll
    for (int i = 0; i < 4; ++i)
      af[i] = *(const bf16x8*)&As[(wm + i*16 + ln)*32 + qd*8];
#pragma unroll
    for (int j = 0; j < 4; ++j)
      bfr[j] = *(const bf16x8*)&Bs[(wn + j*16 + ln)*32 + qd*8];
#pragma unroll
    for (int i = 0; i < 4; ++i)
#pragma unroll
      for (int j = 0; j < 4; ++j)
        acc[i][j] = mfma16(af[i], bfr[j], acc[i][j]);
  }
  const bool isbf = (*flag != 0);
#pragma unroll
  for (int i = 0; i < 4; ++i)
#pragma unroll
    for (int j = 0; j < 4; ++j) {
      int row = m0 + wm + i*16 + qd*4;
      int col = n0 + wn + j*16 + ln;
#pragma unroll
      for (int r = 0; r < 4; ++r) {
        if (isbf) ((__hip_bfloat16*)C)[(size_t)(row + r)*N + col] = __float2bfloat16(acc[i][j][r]);
        else      ((float*)C)[(size_t)(row + r)*N + col] = acc[i][j][r];
      }
    }
}

// RMSNorm + RoPE + (gain/sqrt(HD) for q), in place on the fused qkv buffer.
// r7: vectorized — 2 rows per wave (32 lanes/row), ushort4 load/store
// (2 RoPE pairs per thread). Same per-element math as the scalar version.
__global__ __launch_bounds__(256) void prep_qk(
    __hip_bfloat16* __restrict__ qkv,  // [4096][3072]: q | k | v
    const __hip_bfloat16* __restrict__ gain)
{
  int wid2 = blockIdx.x * 4 + (threadIdx.x >> 6);  // wave id; 2 rows/wave
  int lane = threadIdx.x & 63;
  int half = lane >> 5;
  int l32  = lane & 31;
  int rowid = wid2 * 2 + half;       // 0 .. 81919
  bool isq = rowid < MROWS*NH;
  int m, h;
  __hip_bfloat16* p;
  if (isq) { m = rowid >> 4; h = rowid & 15; p = qkv + (size_t)m*QKVC + h*HDIM; }
  else     { int w2 = rowid - MROWS*NH; m = w2 >> 2; h = w2 & 3; p = qkv + (size_t)m*QKVC + CDIM + h*HDIM; }

  ushort4 raw = *(const ushort4*)((const unsigned short*)p + 4*l32);
  float e0 = bfbits2f(raw.x), o0 = bfbits2f(raw.y);
  float e1 = bfbits2f(raw.z), o1 = bfbits2f(raw.w);
  float ss = (e0*e0 + o0*o0) + (e1*e1 + o1*o1);
#pragma unroll
  for (int off = 16; off >= 1; off >>= 1) ss += __shfl_xor(ss, off);
  float rms = rsqrtf(ss * (1.0f/128.0f) + 1.1920928955078125e-07f);
  e0 *= rms; o0 *= rms; e1 *= rms; o1 *= rms;

  int j0 = 2*l32;                    // this thread's first pair index
  float th0 = exp2f(-(float)(2*j0)     * (1.0f/128.0f) * 13.287712379549449f);
  float th1 = exp2f(-(float)(2*j0 + 2) * (1.0f/128.0f) * 13.287712379549449f);
  int t = m & (TSEQ-1);
  float fr0 = (float)t * th0, fr1 = (float)t * th1;
  float c0 = cosf(fr0), s0 = sinf(fr0);
  float c1 = cosf(fr1), s1 = sinf(fr1);
  float re0 = e0*c0 - o0*s0, ro0 = e0*s0 + o0*c0;
  float re1 = e1*c1 - o1*s1, ro1 = e1*s1 + o1*c1;

  if (isq) {
    float g = bfbits2f(*(const unsigned short*)&gain[h]) * 0.08838834764831845f;
    re0 *= g; ro0 *= g; re1 *= g; ro1 *= g;
  }
  ushort4 outv;
  outv.x = f2bfu(re0); outv.y = f2bfu(ro0);
  outv.z = f2bfu(re1); outv.w = f2bfu(ro1);
  *(ushort4*)((unsigned short*)p + 4*l32) = outv;
}

// v section of qkv [4096][3072] -> vt [B][NKV][HDIM][TSEQ]
__global__ __launch_bounds__(256) void transpose_v(
    const __hip_bfloat16* __restrict__ qkv, __hip_bfloat16* __restrict__ vt)
{
  __shared__ __hip_bfloat16 tile[32][34];
  int tx = threadIdx.x & 31;
  int ty = threadIdx.x >> 5;
  int r0 = blockIdx.x * 32;
  int c0 = blockIdx.y * 32;
#pragma unroll
  for (int i = 0; i < 4; ++i)
    tile[ty + i*8][tx] = qkv[(size_t)(r0 + ty + i*8)*QKVC + (CDIM + KVC) + c0 + tx];
  __syncthreads();
  int b = r0 >> 11;
  int t = r0 & (TSEQ-1);
  int hk = c0 >> 7;
  int d0 = c0 & (HDIM-1);
#pragma unroll
  for (int i = 0; i < 4; ++i) {
    int d = d0 + ty + i*8;
    vt[((size_t)((b*NKV + hk)*HDIM + d))*TSEQ + t + tx] = tile[tx][ty + i*8];
  }
}

// Flash attention v9: balanced pairs {p,31-p}, 4 waves, swapped-operand
// dataflow (verified r4/r5).
__global__ __launch_bounds__(256, 2) void attn_kernel(
    const __hip_bfloat16* __restrict__ qkv, // [B][T][3072] (read-only here)
    const __hip_bfloat16* __restrict__ vt,  // [B][NKV][HD][T]
    __hip_bfloat16* __restrict__ out)       // [B][T][2048] attn output
{
  const int tid  = threadIdx.x;
  const int wave = tid >> 6;   // 0..3
  const int lane = tid & 63;
  const int qd = lane >> 4, ln = lane & 15;
  const int p  = blockIdx.x;     // pair index 0..15 -> q-tiles {p, 31-p}
  const int h  = blockIdx.y;
  const int b  = blockIdx.z;
  const int hk = h >> 2;

  const __hip_bfloat16* K = qkv + (size_t)(b*TSEQ)*QKVC + CDIM + hk*HDIM;
  const __hip_bfloat16* V = vt + ((size_t)(b*NKV + hk)*HDIM)*TSEQ;

  __shared__ __align__(16) __hip_bfloat16 Ks[64*128];  // [t][d], swz128
  __shared__ __align__(16) __hip_bfloat16 Vs[128*64];  // [d][t], swz64
  __shared__ __align__(16) __hip_bfloat16 Pb[64*64];   // P^T as [q][kv], swz64
  __shared__ float Lb[4][64];                          // per-wave l partials

  auto issueK = [&](int t0) {
#pragma unroll
    for (int i = 0; i < 4; ++i) {
      int c = i*256 + tid;             // chunk; 16 chunks/row
      int row = c >> 4, cc = c & 15;
      int gcc = cc ^ (row & 15);
      async16(&K[(size_t)(t0 + row)*QKVC + gcc*8], &Ks[(i*256 + wave*64)*8]);
    }
  };
  auto issueV = [&](int t0) {
#pragma unroll
    for (int i = 0; i < 4; ++i) {
      int c = i*256 + tid;             // chunk; 8 chunks/row
      int row = c >> 3, cc = c & 7;
      int gcc = cc ^ (row & 7);
      async16(&V[(size_t)row*TSEQ + t0 + gcc*8], &Vs[(i*256 + wave*64)*8]);
    }
  };

#pragma unroll 1
  for (int seg = 0; seg < 2; ++seg) {
    const int qt = seg ? (31 - p) : p;
    const int q0 = qt * 64;

    // Q as B-operand fragments (col q = qsub*16+ln, k = kc*32+qd*8+e)
    bf16x8 qfr[4][4];
#pragma unroll
    for (int qsub = 0; qsub < 4; ++qsub)
#pragma unroll
      for (int kc = 0; kc < 4; ++kc)
        qfr[qsub][kc] = *(const bf16x8*)&qkv[((size_t)(b*TSEQ + q0 + qsub*16 + ln))*QKVC + h*HDIM + kc*32 + qd*8];

    // O^T accumulator: o[half][qsub] holds O^T[d = wave*32+half*16+qd*4+r][q = qsub*16+ln]
    f32x4 o[2][4] = {};
    float lacc[4] = {0.f, 0.f, 0.f, 0.f};

    __syncthreads();          // Ks free (prev segment epilogue readback done)
    issueK(0);
    __syncthreads();          // drain K[0]

#pragma unroll 1
    for (int kt = 0; kt <= qt; ++kt) {
      const int t0 = kt * 64;
      issueV(t0);             // Vs free since prev iter-end barrier

      // ---- QK^T swapped: S^T[kv][q], wave owns kv-rows wave*16..+15 ----
      f32x4 sc[4] = {};
#pragma unroll
      for (int kc = 0; kc < 4; ++kc) {
        bf16x8 kfa = *(const bf16x8*)&Ks[swz128(wave*16 + ln, kc*32 + qd*8)];
#pragma unroll
        for (int qsub = 0; qsub < 4; ++qsub)
          sc[qsub] = mfma16(kfa, qfr[qsub][kc], sc[qsub]);
      }
      if (kt == qt) {  // diagonal: causal mask (D: row=kv=qd*4+r, col=q=ln)
#pragma unroll
        for (int qsub = 0; qsub < 4; ++qsub)
#pragma unroll
          for (int r = 0; r < 4; ++r) {
            int kv = t0 + wave*16 + qd*4 + r;
            int q  = q0 + qsub*16 + ln;
            if (kv > q) sc[qsub][r] = -1.0e30f;
          }
      }
      // fixed-offset softmax: p = exp(s), defer l reduction
#pragma unroll
      for (int qsub = 0; qsub < 4; ++qsub) {
#pragma unroll
        for (int r = 0; r < 4; ++r)
          sc[qsub][r] = __expf(sc[qsub][r]);
        lacc[qsub] += (sc[qsub][0] + sc[qsub][1]) + (sc[qsub][2] + sc[qsub][3]);
      }

      // write P^T to Pb[q][kv] (8B packed, swz64; kv = wave*16+qd*4+r)
#pragma unroll
      for (int qsub = 0; qsub < 4; ++qsub) {
        ushort4 pk;
        pk.x = f2bfu(sc[qsub][0]); pk.y = f2bfu(sc[qsub][1]);
        pk.z = f2bfu(sc[qsub][2]); pk.w = f2bfu(sc[qsub][3]);
        *(ushort4*)&Pb[swz64(qsub*16 + ln, wave*16 + qd*4)] = pk;
      }

      __syncthreads();        // P visible; V[kt] drained; Ks consumed by all
      if (kt < qt) issueK(t0 + 64);   // overlaps PV

      // ---- PV d-split: O^T[d][q] += V^T[d][kv] * P^T[kv][q] ----
      __builtin_amdgcn_s_setprio(1);
#pragma unroll
      for (int kc2 = 0; kc2 < 2; ++kc2) {
        bf16x8 pfb[4];
#pragma unroll
        for (int qsub = 0; qsub < 4; ++qsub)
          pfb[qsub] = *(const bf16x8*)&Pb[swz64(qsub*16 + ln, kc2*32 + qd*8)];
#pragma unroll
        for (int half = 0; half < 2; ++half) {
          bf16x8 vfa = *(const bf16x8*)&Vs[swz64(wave*32 + half*16 + ln, kc2*32 + qd*8)];
#pragma unroll
          for (int qsub = 0; qsub < 4; ++qsub)
            o[half][qsub] = mfma16(vfa, pfb[qsub], o[half][qsub]);
        }
      }
      __builtin_amdgcn_s_setprio(0);
      __syncthreads();        // drain K[kt+1]; Vs & Pb free
    }

    // l: reduce across qd groups (kv within wave), then across waves via LDS
#pragma unroll
    for (int qsub = 0; qsub < 4; ++qsub) {
      lacc[qsub] += __shfl_xor(lacc[qsub], 16);
      lacc[qsub] += __shfl_xor(lacc[qsub], 32);
    }
    if (qd == 0) {
#pragma unroll
      for (int qsub = 0; qsub < 4; ++qsub)
        Lb[wave][qsub*16 + ln] = lacc[qsub];
    }
    __syncthreads();
    float inv[4];
#pragma unroll
    for (int qsub = 0; qsub < 4; ++qsub) {
      int q = qsub*16 + ln;
      inv[qsub] = 1.0f / (((Lb[0][q] + Lb[1][q]) + (Lb[2][q] + Lb[3][q])));
    }

    // epilogue: Obuf = Ks reuse, [q 64][d 128] swz128; wave writes its d-cols
#pragma unroll
    for (int half = 0; half < 2; ++half)
#pragma unroll
      for (int qsub = 0; qsub < 4; ++qsub) {
        ushort4 pk;
        pk.x = f2bfu(o[half][qsub][0] * inv[qsub]);
        pk.y = f2bfu(o[half][qsub][1] * inv[qsub]);
        pk.z = f2bfu(o[half][qsub][2] * inv[qsub]);
        pk.w = f2bfu(o[half][qsub][3] * inv[qsub]);
        *(ushort4*)&Ks[swz128(qsub*16 + ln, wave*32 + half*16 + qd*4)] = pk;
      }
    __syncthreads();          // writes visible before readback
#pragma unroll
    for (int pass = 0; pass < 4; ++pass) {
      int row = wave*16 + pass*4 + qd;
      bf16x8 val = *(const bf16x8*)&Ks[swz128(row, ln*8)];
      int q = q0 + row;
      *(bf16x8*)&out[((size_t)(b*TSEQ + q))*CDIM + h*HDIM + ln*8] = val;
    }
  }
}

extern "C" void kernel_launch(void* const* d_in, const int* in_sizes, int n_in,
                              void* d_out, int out_size, void* d_ws, size_t ws_size,
                              hipStream_t stream) {
  char* ws = (char*)d_ws;
  size_t off = 0;
  auto alloc = [&](size_t bytes) { char* p = ws + off; off += (bytes + 255) & ~(size_t)255; return p; };

  int* flag = (int*)alloc(256);
  __hip_bfloat16* xb   = (__hip_bfloat16*)alloc((size_t)MROWS*CDIM*2);   // 16.8 MB (x, then attn out)
  __hip_bfloat16* wqkv = (__hip_bfloat16*)alloc((size_t)QKVC*CDIM*2);    // 12.6 MB
  __hip_bfloat16* wob  = (__hip_bfloat16*)alloc((size_t)CDIM*CDIM*2);    //  8.4 MB
  __hip_bfloat16* gb   = (__hip_bfloat16*)alloc(256);
  __hip_bfloat16* qkv  = (__hip_bfloat16*)alloc((size_t)MROWS*QKVC*2);   // 25.2 MB
  __hip_bfloat16* vt   = (__hip_bfloat16*)alloc((size_t)MROWS*KVC*2);    //  4.2 MB

  canary<<<1, 256, 0, stream>>>(d_in[0], flag);

  canonize_all<<<9217, 256, 0, stream>>>(
      d_in[0], d_in[1], d_in[2], d_in[3], d_in[4], d_in[5],
      xb, wqkv, wob, gb, flag);

  // fused QKV projection: BM=256 x BN=192 -> grid 16x16 = 256 blocks = 1/CU.
  gemm_bt256<<<dim3(QKVC/192, MROWS/256), 512, 0, stream>>>(
      xb, wqkv, qkv, MROWS, QKVC, CDIM, CDIM);

  // prep: 2 rows/wave -> (81920 rows / 2) / 4 waves = 10240 blocks
  prep_qk<<<(MROWS*NH + MROWS*NKV)/8, 256, 0, stream>>>(qkv, gb);

  transpose_v<<<dim3(MROWS/32, KVC/32), 256, 0, stream>>>(qkv, vt);

  // attention: balanced pairs {p, 31-p}, 256-thread blocks, swapped-operand
  attn_kernel<<<dim3(16, NH, BATCH), 256, 0, stream>>>(qkv, vt, xb);

  // output projection: r0-verified 128x128, grid 16x32 = 512 blocks (2/CU)
  gemm_out<<<dim3(CDIM/128, MROWS/128), 256, 0, stream>>>(
      xb, wob, d_out, MROWS, CDIM, CDIM, CDIM, flag);
}

// Round 8
// 284.639 us; speedup vs baseline: 1.0418x; 1.0285x over previous
//
#include <hip/hip_runtime.h>
#include <hip/hip_bf16.h>

#define TSEQ 2048
#define CDIM 2048
#define NH   16
#define NKV  4
#define HDIM 128
#define BATCH 2
#define MROWS (BATCH*TSEQ)   // 4096
#define KVC   (NKV*HDIM)     // 512
#define QKVC  (CDIM + 2*KVC) // 3072: fused qkv row stride

typedef short bf16x8 __attribute__((ext_vector_type(8)));
typedef float f32x4  __attribute__((ext_vector_type(4)));

typedef const __attribute__((address_space(1))) void* gptr_t;
typedef __attribute__((address_space(3))) void* sptr_t;

__device__ inline void async16(const __hip_bfloat16* g, __hip_bfloat16* l) {
  __builtin_amdgcn_global_load_lds((gptr_t)g, (sptr_t)l, 16, 0, 0);
}

__device__ inline f32x4 mfma16(bf16x8 a, bf16x8 b, f32x4 c) {
  return __builtin_amdgcn_mfma_f32_16x16x32_bf16(a, b, c, 0, 0, 0);
}

__device__ inline float bfbits2f(unsigned short u) {
  return __uint_as_float(((unsigned)u) << 16);
}

__device__ inline unsigned short f2bfu(float x) {
  __hip_bfloat16 t = __float2bfloat16(x);
  return *(unsigned short*)&t;
}

// Per-wave dtype detect (replaces the canary kernel + flag round-trip).
// Samples the first 256 even ushorts of x (identical indices for every wave
// -> deterministic, uniform verdict). bf16 data: |v| in [1e-6,1e3] ~always
// (cnt ~256 > 128). f32 data: even ushorts are mantissa low-halves -> random
// exponent, pass-rate ~12% (cnt ~31 < 128). Same statistics as the old
// canary (1024 samples > 512).
__device__ inline bool detect_bf16(const void* x) {
  const unsigned short* u = (const unsigned short*)x;
  int lane = threadIdx.x & 63;
  int c = 0;
#pragma unroll
  for (int i = 0; i < 4; ++i) {
    float a = fabsf(bfbits2f(u[(lane*4 + i)*2]));
    if (a >= 1e-6f && a <= 1e3f) c++;
  }
#pragma unroll
  for (int off = 32; off >= 1; off >>= 1) c += __shfl_xor(c, off);
  return c > 128;
}

// LDS XOR-swizzles: break row-stride bank aliasing for 16B fragment access.
__device__ inline int swz128(int row, int col) {  // rows of 128 bf16
  return row*128 + (((col >> 3) ^ (row & 15)) << 3) + (col & 7);
}
__device__ inline int swz64(int row, int col) {   // rows of 64 bf16
  return row*64 + ((((col >> 3) ^ row) & 7) << 3) + (col & 7);
}

// ---- canonize ALL inputs in one launch; per-wave dtype self-detect ----
__global__ __launch_bounds__(256) void canonize_all(
    const void* __restrict__ xs,  const void* __restrict__ wqs,
    const void* __restrict__ wks, const void* __restrict__ wvs,
    const void* __restrict__ wos, const void* __restrict__ gs,
    __hip_bfloat16* __restrict__ xd,   // [4096][2048]
    __hip_bfloat16* __restrict__ wqkv, // [3072][2048] (Wq;Wk;Wv rows)
    __hip_bfloat16* __restrict__ wod,  // [2048][2048]
    __hip_bfloat16* __restrict__ gd)   // [16]
{
  const bool isbf = detect_bf16(xs);   // whole wave, before any divergence
  int blk = blockIdx.x;
  const void* src; __hip_bfloat16* dst; int base, n;
  if      (blk < 4096) { src = xs;  dst = xd;                base = blk;        n = MROWS*CDIM; }
  else if (blk < 6144) { src = wqs; dst = wqkv;              base = blk - 4096; n = CDIM*CDIM; }
  else if (blk < 6656) { src = wks; dst = wqkv + (size_t)CDIM*CDIM;            base = blk - 6144; n = KVC*CDIM; }
  else if (blk < 7168) { src = wvs; dst = wqkv + (size_t)(CDIM+KVC)*CDIM;      base = blk - 6656; n = KVC*CDIM; }
  else if (blk < 9216) { src = wos; dst = wod;               base = blk - 7168; n = CDIM*CDIM; }
  else                 { src = gs;  dst = gd;                base = 0;          n = NH; }
  int idx = base*2048 + threadIdx.x*8;
  if (idx >= n) return;
  if (isbf) {
    *(bf16x8*)&dst[idx] = *(const bf16x8*)((const __hip_bfloat16*)src + idx);
  } else {
    const float* s = (const float*)src + idx;
    float4 f0 = *(const float4*)s;
    float4 f1 = *(const float4*)(s + 4);
    union { bf16x8 v; unsigned short u[8]; } o;
    o.u[0] = f2bfu(f0.x); o.u[1] = f2bfu(f0.y);
    o.u[2] = f2bfu(f0.z); o.u[3] = f2bfu(f0.w);
    o.u[4] = f2bfu(f1.x); o.u[5] = f2bfu(f1.y);
    o.u[6] = f2bfu(f1.z); o.u[7] = f2bfu(f1.w);
    *(bf16x8*)&dst[idx] = o.v;
  }
}

// ---------------------------------------------------------------------------
// QKV GEMM: BM=256 x BN=192, BK=64. Grid 16x16 = 256 blocks = 1/CU.
// r8: 3-deep A rotation (LDS 144 KiB) enables SPREAD staging (the m196
// "fine interleave" lever) instead of r5's bunched P3/P4 staging:
//  P1: ds a03(bufA),b01(bufB) ; stage A-half0(t+2)->nextA ; MFMA Q1 ; barrier
//  P2: ds a47(bufA)           ; stage A-half1(t+2)->nextA ; MFMA Q2 ; barrier
//  P3: ds b2(bufB)            ;                             MFMA Q3 ; barrier
//  P4: stage B(t+2)->bufB     ; MFMA Q4 ; vmcnt(7) ; barrier
// Hazards: nextA=(t+2)%3 != bufA=t%3 -> P1/P2 staging never collides with
// this tile's A reads; As[nextA]'s last readers were tile t-1 (same index),
// done chip-wide at t-1's P2-end barrier. B is 2-deep: B(t) reads complete
// at P3-end barrier -> P4 stage safe. Gate leaves exactly t+2's 7 loads
// outstanding -> t+1 certified resident for next P1.
// ---------------------------------------------------------------------------
#define BK 64

__global__ __launch_bounds__(512, 2) void gemm_bt256(
    const __hip_bfloat16* __restrict__ A,
    const __hip_bfloat16* __restrict__ B,
    __hip_bfloat16* __restrict__ C,
    int M, int N, int K, int lda)
{
  __shared__ __align__(16) __hip_bfloat16 As[3][256*BK];  // 96 KiB
  __shared__ __align__(16) __hip_bfloat16 Bs[2][192*BK];  // 48 KiB
  const int tid  = threadIdx.x;
  const int wave = tid >> 6;
  const int lane = tid & 63;
  const int qd   = lane >> 4;
  const int ln   = lane & 15;
  const int m0   = blockIdx.y * 256;
  const int n0   = blockIdx.x * 192;
  const int wm   = (wave >> 2) * 128;  // 2 wave-rows
  const int wn   = (wave & 3) * 48;    // 4 wave-cols

  // A half: 128 rows x 64 cols = 1024 chunks -> 2 loads/thread.
  auto stageAhalf = [&](int buf, int kt, int half) {
    const __hip_bfloat16* src = A + (size_t)(m0 + half*128)*lda + kt*BK;
    __hip_bfloat16* dst = &As[buf][half*128*BK];
#pragma unroll
    for (int i = 0; i < 2; ++i) {
      int c = i*512 + tid;
      int row = c >> 3, sl = c & 7;
      int gs = sl ^ (row & 7);
      async16(&src[(size_t)row*lda + gs*8], &dst[(i*512 + wave*64)*8]);
    }
  };
  // B: 192x64 = 1536 chunks -> 3 loads/thread.
  auto stageB = [&](int buf, int kt) {
    const __hip_bfloat16* src = B + (size_t)n0*K + kt*BK;
    __hip_bfloat16* dst = &Bs[buf][0];
#pragma unroll
    for (int i = 0; i < 3; ++i) {
      int c = i*512 + tid;
      int row = c >> 3, sl = c & 7;
      int gs = sl ^ (row & 7);
      async16(&src[(size_t)row*K + gs*8], &dst[(i*512 + wave*64)*8]);
    }
  };
  auto ldA = [&](int buf, int m, int kk) -> bf16x8 {
    int row = wm + m*16 + ln;
    return *(const bf16x8*)&As[buf][row*BK + (((kk*4 + qd) ^ (row & 7)) << 3)];
  };
  auto ldB = [&](int buf, int n, int kk) -> bf16x8 {
    int row = wn + n*16 + ln;
    return *(const bf16x8*)&Bs[buf][row*BK + (((kk*4 + qd) ^ (row & 7)) << 3)];
  };

  f32x4 acc[8][3] = {};
  const int nt = K / BK;

  // prologue: tiles 0,1 fully staged (14 loads); retire tile0 (leave 7).
  stageAhalf(0, 0, 0); stageAhalf(0, 0, 1); stageB(0, 0);
  if (nt > 1) {
    stageAhalf(1, 1, 0); stageAhalf(1, 1, 1); stageB(1, 1);
    asm volatile("s_waitcnt vmcnt(7)" ::: "memory");
  } else {
    asm volatile("s_waitcnt vmcnt(0)" ::: "memory");
  }
  __builtin_amdgcn_s_barrier();

#pragma unroll 1
  for (int t = 0; t < nt; ++t) {
    const int bufA = t % 3;
    const int bufB = t & 1;
    int nextA = bufA + 2; if (nextA >= 3) nextA -= 3;
    const bool pre = (t + 2 < nt);
    bf16x8 a03[4][2], a47[4][2], b01[2][2], b2[2];

    // ---- P1: ds a03 + b01; stage A-half0(t+2); MFMA Q1 ----
#pragma unroll
    for (int m = 0; m < 4; ++m)
#pragma unroll
      for (int kk = 0; kk < 2; ++kk) a03[m][kk] = ldA(bufA, m, kk);
#pragma unroll
    for (int n = 0; n < 2; ++n)
#pragma unroll
      for (int kk = 0; kk < 2; ++kk) b01[n][kk] = ldB(bufB, n, kk);
    if (pre) stageAhalf(nextA, t + 2, 0);
    __builtin_amdgcn_s_setprio(1);
#pragma unroll
    for (int m = 0; m < 4; ++m)
#pragma unroll
      for (int n = 0; n < 2; ++n)
#pragma unroll
        for (int kk = 0; kk < 2; ++kk)
          acc[m][n] = mfma16(a03[m][kk], b01[n][kk], acc[m][n]);
    __builtin_amdgcn_s_setprio(0);
    __builtin_amdgcn_s_barrier();

    // ---- P2: ds a47; stage A-half1(t+2); MFMA Q2 ----
#pragma unroll
    for (int m = 0; m < 4; ++m)
#pragma unroll
      for (int kk = 0; kk < 2; ++kk) a47[m][kk] = ldA(bufA, 4 + m, kk);
    if (pre) stageAhalf(nextA, t + 2, 1);
    __builtin_amdgcn_s_setprio(1);
#pragma unroll
    for (int m = 0; m < 4; ++m)
#pragma unroll
      for (int n = 0; n < 2; ++n)
#pragma unroll
        for (int kk = 0; kk < 2; ++kk)
          acc[4 + m][n] = mfma16(a47[m][kk], b01[n][kk], acc[4 + m][n]);
    __builtin_amdgcn_s_setprio(0);
    __builtin_amdgcn_s_barrier();

    // ---- P3: ds b2; MFMA Q3 ----
#pragma unroll
    for (int kk = 0; kk < 2; ++kk) b2[kk] = ldB(bufB, 2, kk);
    __builtin_amdgcn_s_setprio(1);
#pragma unroll
    for (int m = 0; m < 4; ++m)
#pragma unroll
      for (int kk = 0; kk < 2; ++kk)
        acc[m][2] = mfma16(a03[m][kk], b2[kk], acc[m][2]);
    __builtin_amdgcn_s_setprio(0);
    __builtin_amdgcn_s_barrier();

    // ---- P4: stage B(t+2); MFMA Q4; gate ----
    if (pre) stageB(bufB, t + 2);
    __builtin_amdgcn_s_setprio(1);
#pragma unroll
    for (int m = 0; m < 4; ++m)
#pragma unroll
      for (int kk = 0; kk < 2; ++kk)
        acc[4 + m][2] = mfma16(a47[m][kk], b2[kk], acc[4 + m][2]);
    __builtin_amdgcn_s_setprio(0);
    if (pre) asm volatile("s_waitcnt vmcnt(7)" ::: "memory");
    else     asm volatile("s_waitcnt vmcnt(0)" ::: "memory");
    __builtin_amdgcn_s_barrier();
  }

#pragma unroll
  for (int m = 0; m < 8; ++m)
#pragma unroll
    for (int n = 0; n < 3; ++n) {
      int row = m0 + wm + m*16 + qd*4;
      int col = n0 + wn + n*16 + ln;
#pragma unroll
      for (int r = 0; r < 4; ++r)
        C[(size_t)(row + r)*N + col] = __float2bfloat16(acc[m][n][r]);
    }
}

// ---------------------------------------------------------------------------
// Output GEMM: r0-verified 128x128 BK=32 structure (2 blocks/CU, 512
// balanced blocks) + per-wave dtype self-detect for the epilogue.
// ---------------------------------------------------------------------------
__global__ __launch_bounds__(256, 2) void gemm_out(
    const __hip_bfloat16* __restrict__ A,
    const __hip_bfloat16* __restrict__ B,
    void* __restrict__ C,
    int M, int N, int K, int lda, const void* __restrict__ xorig)
{
  const bool isbf = detect_bf16(xorig);
  __shared__ __align__(16) __hip_bfloat16 As[128*32];
  __shared__ __align__(16) __hip_bfloat16 Bs[128*32];
  const int tid  = threadIdx.x;
  const int wave = tid >> 6;
  const int lane = tid & 63;
  const int qd   = lane >> 4;
  const int ln   = lane & 15;
  const int m0   = blockIdx.y * 128;
  const int n0   = blockIdx.x * 128;
  const int wm   = (wave >> 1) * 64;
  const int wn   = (wave & 1) * 64;

  f32x4 acc[4][4] = {};

  for (int k0 = 0; k0 < K; k0 += 32) {
    __syncthreads();
#pragma unroll
    for (int r = 0; r < 2; ++r) {
      int e   = (r*256 + tid) * 8;
      int row = e >> 5;
      int col = e & 31;
      async16(&A[(size_t)(m0+row)*lda + k0 + col], &As[(size_t)(r*256 + wave*64)*8]);
      async16(&B[(size_t)(n0+row)*K   + k0 + col], &Bs[(size_t)(r*256 + wave*64)*8]);
    }
    __syncthreads();
    bf16x8 af[4], bfr[4];
#pragma unroll
    for (int i = 0; i < 4; ++i)
      af[i] = *(const bf16x8*)&As[(wm + i*16 + ln)*32 + qd*8];
#pragma unroll
    for (int j = 0; j < 4; ++j)
      bfr[j] = *(const bf16x8*)&Bs[(wn + j*16 + ln)*32 + qd*8];
#pragma unroll
    for (int i = 0; i < 4; ++i)
#pragma unroll
      for (int j = 0; j < 4; ++j)
        acc[i][j] = mfma16(af[i], bfr[j], acc[i][j]);
  }
#pragma unroll
  for (int i = 0; i < 4; ++i)
#pragma unroll
    for (int j = 0; j < 4; ++j) {
      int row = m0 + wm + i*16 + qd*4;
      int col = n0 + wn + j*16 + ln;
#pragma unroll
      for (int r = 0; r < 4; ++r) {
        if (isbf) ((__hip_bfloat16*)C)[(size_t)(row + r)*N + col] = __float2bfloat16(acc[i][j][r]);
        else      ((float*)C)[(size_t)(row + r)*N + col] = acc[i][j][r];
      }
    }
}

// ---------------------------------------------------------------------------
// Fused prep (RMSNorm+RoPE+gain on q,k) + transpose_v. The two parts touch
// disjoint qkv columns (prep: [0,2560); transpose reads [2560,3072)) so they
// run concurrently in one launch. Blocks [0,10240): prep (2 rows/wave,
// ushort4); blocks [10240,12288): 32x32 transpose tiles.
// ---------------------------------------------------------------------------
__global__ __launch_bounds__(256) void prep_and_tv(
    __hip_bfloat16* __restrict__ qkv,  // [4096][3072]: q | k | v
    const __hip_bfloat16* __restrict__ gain,
    __hip_bfloat16* __restrict__ vt)   // [B][NKV][HDIM][TSEQ]
{
  int blk = blockIdx.x;
  if (blk < 10240) {
    int wid2 = blk * 4 + (threadIdx.x >> 6);  // wave id; 2 rows/wave
    int lane = threadIdx.x & 63;
    int half = lane >> 5;
    int l32  = lane & 31;
    int rowid = wid2 * 2 + half;       // 0 .. 81919
    bool isq = rowid < MROWS*NH;
    int m, h;
    __hip_bfloat16* p;
    if (isq) { m = rowid >> 4; h = rowid & 15; p = qkv + (size_t)m*QKVC + h*HDIM; }
    else     { int w2 = rowid - MROWS*NH; m = w2 >> 2; h = w2 & 3; p = qkv + (size_t)m*QKVC + CDIM + h*HDIM; }

    ushort4 raw = *(const ushort4*)((const unsigned short*)p + 4*l32);
    float e0 = bfbits2f(raw.x), o0 = bfbits2f(raw.y);
    float e1 = bfbits2f(raw.z), o1 = bfbits2f(raw.w);
    float ss = (e0*e0 + o0*o0) + (e1*e1 + o1*o1);
#pragma unroll
    for (int off = 16; off >= 1; off >>= 1) ss += __shfl_xor(ss, off);
    float rms = rsqrtf(ss * (1.0f/128.0f) + 1.1920928955078125e-07f);
    e0 *= rms; o0 *= rms; e1 *= rms; o1 *= rms;

    int j0 = 2*l32;
    float th0 = exp2f(-(float)(2*j0)     * (1.0f/128.0f) * 13.287712379549449f);
    float th1 = exp2f(-(float)(2*j0 + 2) * (1.0f/128.0f) * 13.287712379549449f);
    int t = m & (TSEQ-1);
    float fr0 = (float)t * th0, fr1 = (float)t * th1;
    float c0 = cosf(fr0), s0 = sinf(fr0);
    float c1 = cosf(fr1), s1 = sinf(fr1);
    float re0 = e0*c0 - o0*s0, ro0 = e0*s0 + o0*c0;
    float re1 = e1*c1 - o1*s1, ro1 = e1*s1 + o1*c1;

    if (isq) {
      float g = bfbits2f(*(const unsigned short*)&gain[h]) * 0.08838834764831845f;
      re0 *= g; ro0 *= g; re1 *= g; ro1 *= g;
    }
    ushort4 outv;
    outv.x = f2bfu(re0); outv.y = f2bfu(ro0);
    outv.z = f2bfu(re1); outv.w = f2bfu(ro1);
    *(ushort4*)((unsigned short*)p + 4*l32) = outv;
  } else {
    __shared__ __hip_bfloat16 tile[32][34];
    int bx = blk - 10240;
    int tx = threadIdx.x & 31;
    int ty = threadIdx.x >> 5;
    int r0 = (bx & 127) * 32;
    int c0 = (bx >> 7) * 32;
#pragma unroll
    for (int i = 0; i < 4; ++i)
      tile[ty + i*8][tx] = qkv[(size_t)(r0 + ty + i*8)*QKVC + (CDIM + KVC) + c0 + tx];
    __syncthreads();
    int b = r0 >> 11;
    int t = r0 & (TSEQ-1);
    int hk = c0 >> 7;
    int d0 = c0 & (HDIM-1);
#pragma unroll
    for (int i = 0; i < 4; ++i) {
      int d = d0 + ty + i*8;
      vt[((size_t)((b*NKV + hk)*HDIM + d))*TSEQ + t + tx] = tile[tx][ty + i*8];
    }
  }
}

// Flash attention v9: balanced pairs {p,31-p}, 4 waves, swapped-operand
// dataflow (verified r4-r7).
__global__ __launch_bounds__(256, 2) void attn_kernel(
    const __hip_bfloat16* __restrict__ qkv, // [B][T][3072] (read-only here)
    const __hip_bfloat16* __restrict__ vt,  // [B][NKV][HD][T]
    __hip_bfloat16* __restrict__ out)       // [B][T][2048] attn output
{
  const int tid  = threadIdx.x;
  const int wave = tid >> 6;   // 0..3
  const int lane = tid & 63;
  const int qd = lane >> 4, ln = lane & 15;
  const int p  = blockIdx.x;     // pair index 0..15 -> q-tiles {p, 31-p}
  const int h  = blockIdx.y;
  const int b  = blockIdx.z;
  const int hk = h >> 2;

  const __hip_bfloat16* K = qkv + (size_t)(b*TSEQ)*QKVC + CDIM + hk*HDIM;
  const __hip_bfloat16* V = vt + ((size_t)(b*NKV + hk)*HDIM)*TSEQ;

  __shared__ __align__(16) __hip_bfloat16 Ks[64*128];  // [t][d], swz128
  __shared__ __align__(16) __hip_bfloat16 Vs[128*64];  // [d][t], swz64
  __shared__ __align__(16) __hip_bfloat16 Pb[64*64];   // P^T as [q][kv], swz64
  __shared__ float Lb[4][64];                          // per-wave l partials

  auto issueK = [&](int t0) {
#pragma unroll
    for (int i = 0; i < 4; ++i) {
      int c = i*256 + tid;             // chunk; 16 chunks/row
      int row = c >> 4, cc = c & 15;
      int gcc = cc ^ (row & 15);
      async16(&K[(size_t)(t0 + row)*QKVC + gcc*8], &Ks[(i*256 + wave*64)*8]);
    }
  };
  auto issueV = [&](int t0) {
#pragma unroll
    for (int i = 0; i < 4; ++i) {
      int c = i*256 + tid;             // chunk; 8 chunks/row
      int row = c >> 3, cc = c & 7;
      int gcc = cc ^ (row & 7);
      async16(&V[(size_t)row*TSEQ + t0 + gcc*8], &Vs[(i*256 + wave*64)*8]);
    }
  };

#pragma unroll 1
  for (int seg = 0; seg < 2; ++seg) {
    const int qt = seg ? (31 - p) : p;
    const int q0 = qt * 64;

    // Q as B-operand fragments (col q = qsub*16+ln, k = kc*32+qd*8+e)
    bf16x8 qfr[4][4];
#pragma unroll
    for (int qsub = 0; qsub < 4; ++qsub)
#pragma unroll
      for (int kc = 0; kc < 4; ++kc)
        qfr[qsub][kc] = *(const bf16x8*)&qkv[((size_t)(b*TSEQ + q0 + qsub*16 + ln))*QKVC + h*HDIM + kc*32 + qd*8];

    // O^T accumulator: o[half][qsub] holds O^T[d = wave*32+half*16+qd*4+r][q = qsub*16+ln]
    f32x4 o[2][4] = {};
    float lacc[4] = {0.f, 0.f, 0.f, 0.f};

    __syncthreads();          // Ks free (prev segment epilogue readback done)
    issueK(0);
    __syncthreads();          // drain K[0]

#pragma unroll 1
    for (int kt = 0; kt <= qt; ++kt) {
      const int t0 = kt * 64;
      issueV(t0);             // Vs free since prev iter-end barrier

      // ---- QK^T swapped: S^T[kv][q], wave owns kv-rows wave*16..+15 ----
      f32x4 sc[4] = {};
#pragma unroll
      for (int kc = 0; kc < 4; ++kc) {
        bf16x8 kfa = *(const bf16x8*)&Ks[swz128(wave*16 + ln, kc*32 + qd*8)];
#pragma unroll
        for (int qsub = 0; qsub < 4; ++qsub)
          sc[qsub] = mfma16(kfa, qfr[qsub][kc], sc[qsub]);
      }
      if (kt == qt) {  // diagonal: causal mask (D: row=kv=qd*4+r, col=q=ln)
#pragma unroll
        for (int qsub = 0; qsub < 4; ++qsub)
#pragma unroll
          for (int r = 0; r < 4; ++r) {
            int kv = t0 + wave*16 + qd*4 + r;
            int q  = q0 + qsub*16 + ln;
            if (kv > q) sc[qsub][r] = -1.0e30f;
          }
      }
      // fixed-offset softmax: p = exp(s), defer l reduction
#pragma unroll
      for (int qsub = 0; qsub < 4; ++qsub) {
#pragma unroll
        for (int r = 0; r < 4; ++r)
          sc[qsub][r] = __expf(sc[qsub][r]);
        lacc[qsub] += (sc[qsub][0] + sc[qsub][1]) + (sc[qsub][2] + sc[qsub][3]);
      }

      // write P^T to Pb[q][kv] (8B packed, swz64; kv = wave*16+qd*4+r)
#pragma unroll
      for (int qsub = 0; qsub < 4; ++qsub) {
        ushort4 pk;
        pk.x = f2bfu(sc[qsub][0]); pk.y = f2bfu(sc[qsub][1]);
        pk.z = f2bfu(sc[qsub][2]); pk.w = f2bfu(sc[qsub][3]);
        *(ushort4*)&Pb[swz64(qsub*16 + ln, wave*16 + qd*4)] = pk;
      }

      __syncthreads();        // P visible; V[kt] drained; Ks consumed by all
      if (kt < qt) issueK(t0 + 64);   // overlaps PV

      // ---- PV d-split: O^T[d][q] += V^T[d][kv] * P^T[kv][q] ----
      __builtin_amdgcn_s_setprio(1);
#pragma unroll
      for (int kc2 = 0; kc2 < 2; ++kc2) {
        bf16x8 pfb[4];
#pragma unroll
        for (int qsub = 0; qsub < 4; ++qsub)
          pfb[qsub] = *(const bf16x8*)&Pb[swz64(qsub*16 + ln, kc2*32 + qd*8)];
#pragma unroll
        for (int half = 0; half < 2; ++half) {
          bf16x8 vfa = *(const bf16x8*)&Vs[swz64(wave*32 + half*16 + ln, kc2*32 + qd*8)];
#pragma unroll
          for (int qsub = 0; qsub < 4; ++qsub)
            o[half][qsub] = mfma16(vfa, pfb[qsub], o[half][qsub]);
        }
      }
      __builtin_amdgcn_s_setprio(0);
      __syncthreads();        // drain K[kt+1]; Vs & Pb free
    }

    // l: reduce across qd groups (kv within wave), then across waves via LDS
#pragma unroll
    for (int qsub = 0; qsub < 4; ++qsub) {
      lacc[qsub] += __shfl_xor(lacc[qsub], 16);
      lacc[qsub] += __shfl_xor(lacc[qsub], 32);
    }
    if (qd == 0) {
#pragma unroll
      for (int qsub = 0; qsub < 4; ++qsub)
        Lb[wave][qsub*16 + ln] = lacc[qsub];
    }
    __syncthreads();
    float inv[4];
#pragma unroll
    for (int qsub = 0; qsub < 4; ++qsub) {
      int q = qsub*16 + ln;
      inv[qsub] = 1.0f / (((Lb[0][q] + Lb[1][q]) + (Lb[2][q] + Lb[3][q])));
    }

    // epilogue: Obuf = Ks reuse, [q 64][d 128] swz128; wave writes its d-cols
#pragma unroll
    for (int half = 0; half < 2; ++half)
#pragma unroll
      for (int qsub = 0; qsub < 4; ++qsub) {
        ushort4 pk;
        pk.x = f2bfu(o[half][qsub][0] * inv[qsub]);
        pk.y = f2bfu(o[half][qsub][1] * inv[qsub]);
        pk.z = f2bfu(o[half][qsub][2] * inv[qsub]);
        pk.w = f2bfu(o[half][qsub][3] * inv[qsub]);
        *(ushort4*)&Ks[swz128(qsub*16 + ln, wave*32 + half*16 + qd*4)] = pk;
      }
    __syncthreads();          // writes visible before readback
#pragma unroll
    for (int pass = 0; pass < 4; ++pass) {
      int row = wave*16 + pass*4 + qd;
      bf16x8 val = *(const bf16x8*)&Ks[swz128(row, ln*8)];
      int q = q0 + row;
      *(bf16x8*)&out[((size_t)(b*TSEQ + q))*CDIM + h*HDIM + ln*8] = val;
    }
  }
}

extern "C" void kernel_launch(void* const* d_in, const int* in_sizes, int n_in,
                              void* d_out, int out_size, void* d_ws, size_t ws_size,
                              hipStream_t stream) {
  char* ws = (char*)d_ws;
  size_t off = 0;
  auto alloc = [&](size_t bytes) { char* p = ws + off; off += (bytes + 255) & ~(size_t)255; return p; };

  __hip_bfloat16* xb   = (__hip_bfloat16*)alloc((size_t)MROWS*CDIM*2);   // 16.8 MB (x, then attn out)
  __hip_bfloat16* wqkv = (__hip_bfloat16*)alloc((size_t)QKVC*CDIM*2);    // 12.6 MB
  __hip_bfloat16* wob  = (__hip_bfloat16*)alloc((size_t)CDIM*CDIM*2);    //  8.4 MB
  __hip_bfloat16* gb   = (__hip_bfloat16*)alloc(256);
  __hip_bfloat16* qkv  = (__hip_bfloat16*)alloc((size_t)MROWS*QKVC*2);   // 25.2 MB
  __hip_bfloat16* vt   = (__hip_bfloat16*)alloc((size_t)MROWS*KVC*2);    //  4.2 MB

  // 1) canonize (per-wave dtype self-detect; no canary kernel)
  canonize_all<<<9217, 256, 0, stream>>>(
      d_in[0], d_in[1], d_in[2], d_in[3], d_in[4], d_in[5],
      xb, wqkv, wob, gb);

  // 2) fused QKV projection: BM=256 x BN=192 -> 256 blocks = 1/CU
  gemm_bt256<<<dim3(QKVC/192, MROWS/256), 512, 0, stream>>>(
      xb, wqkv, qkv, MROWS, QKVC, CDIM, CDIM);

  // 3) fused prep(q,k) + transpose_v: 10240 + 2048 blocks
  prep_and_tv<<<12288, 256, 0, stream>>>(qkv, gb, vt);

  // 4) attention: balanced pairs {p, 31-p}, swapped-operand
  attn_kernel<<<dim3(16, NH, BATCH), 256, 0, stream>>>(qkv, vt, xb);

  // 5) output projection: r0-verified 128x128, 512 blocks (2/CU)
  gemm_out<<<dim3(CDIM/128, MROWS/128), 256, 0, stream>>>(
      xb, wob, d_out, MROWS, CDIM, CDIM, CDIM, d_in[0]);
}

// Round 9
// 283.062 us; speedup vs baseline: 1.0476x; 1.0056x over previous
//
#include <hip/hip_runtime.h>
#include <hip/hip_bf16.h>

#define TSEQ 2048
#define CDIM 2048
#define NH   16
#define NKV  4
#define HDIM 128
#define BATCH 2
#define MROWS (BATCH*TSEQ)   // 4096
#define KVC   (NKV*HDIM)     // 512
#define QKVC  (CDIM + 2*KVC) // 3072: fused qkv row stride

typedef short bf16x8 __attribute__((ext_vector_type(8)));
typedef float f32x4  __attribute__((ext_vector_type(4)));
typedef float f32x16 __attribute__((ext_vector_type(16)));

typedef const __attribute__((address_space(1))) void* gptr_t;
typedef __attribute__((address_space(3))) void* sptr_t;

__device__ inline void async16(const __hip_bfloat16* g, __hip_bfloat16* l) {
  __builtin_amdgcn_global_load_lds((gptr_t)g, (sptr_t)l, 16, 0, 0);
}

__device__ inline f32x4 mfma16(bf16x8 a, bf16x8 b, f32x4 c) {
  return __builtin_amdgcn_mfma_f32_16x16x32_bf16(a, b, c, 0, 0, 0);
}

__device__ inline f32x16 mfma32(bf16x8 a, bf16x8 b, f32x16 c) {
  return __builtin_amdgcn_mfma_f32_32x32x16_bf16(a, b, c, 0, 0, 0);
}

__device__ inline float bfbits2f(unsigned short u) {
  return __uint_as_float(((unsigned)u) << 16);
}

__device__ inline unsigned short f2bfu(float x) {
  __hip_bfloat16 t = __float2bfloat16(x);
  return *(unsigned short*)&t;
}

// Per-wave dtype detect (replaces the canary kernel + flag round-trip).
__device__ inline bool detect_bf16(const void* x) {
  const unsigned short* u = (const unsigned short*)x;
  int lane = threadIdx.x & 63;
  int c = 0;
#pragma unroll
  for (int i = 0; i < 4; ++i) {
    float a = fabsf(bfbits2f(u[(lane*4 + i)*2]));
    if (a >= 1e-6f && a <= 1e3f) c++;
  }
#pragma unroll
  for (int off = 32; off >= 1; off >>= 1) c += __shfl_xor(c, off);
  return c > 128;
}

// LDS XOR-swizzles: break row-stride bank aliasing for 16B fragment access.
__device__ inline int swz128(int row, int col) {  // rows of 128 bf16
  return row*128 + (((col >> 3) ^ (row & 15)) << 3) + (col & 7);
}
__device__ inline int swz64(int row, int col) {   // rows of 64 bf16
  return row*64 + ((((col >> 3) ^ row) & 7) << 3) + (col & 7);
}

// ---- canonize ALL inputs in one launch; per-wave dtype self-detect ----
__global__ __launch_bounds__(256) void canonize_all(
    const void* __restrict__ xs,  const void* __restrict__ wqs,
    const void* __restrict__ wks, const void* __restrict__ wvs,
    const void* __restrict__ wos, const void* __restrict__ gs,
    __hip_bfloat16* __restrict__ xd,   // [4096][2048]
    __hip_bfloat16* __restrict__ wqkv, // [3072][2048] (Wq;Wk;Wv rows)
    __hip_bfloat16* __restrict__ wod,  // [2048][2048]
    __hip_bfloat16* __restrict__ gd)   // [16]
{
  const bool isbf = detect_bf16(xs);   // whole wave, before any divergence
  int blk = blockIdx.x;
  const void* src; __hip_bfloat16* dst; int base, n;
  if      (blk < 4096) { src = xs;  dst = xd;                base = blk;        n = MROWS*CDIM; }
  else if (blk < 6144) { src = wqs; dst = wqkv;              base = blk - 4096; n = CDIM*CDIM; }
  else if (blk < 6656) { src = wks; dst = wqkv + (size_t)CDIM*CDIM;            base = blk - 6144; n = KVC*CDIM; }
  else if (blk < 7168) { src = wvs; dst = wqkv + (size_t)(CDIM+KVC)*CDIM;      base = blk - 6656; n = KVC*CDIM; }
  else if (blk < 9216) { src = wos; dst = wod;               base = blk - 7168; n = CDIM*CDIM; }
  else                 { src = gs;  dst = gd;                base = 0;          n = NH; }
  int idx = base*2048 + threadIdx.x*8;
  if (idx >= n) return;
  if (isbf) {
    *(bf16x8*)&dst[idx] = *(const bf16x8*)((const __hip_bfloat16*)src + idx);
  } else {
    const float* s = (const float*)src + idx;
    float4 f0 = *(const float4*)s;
    float4 f1 = *(const float4*)(s + 4);
    union { bf16x8 v; unsigned short u[8]; } o;
    o.u[0] = f2bfu(f0.x); o.u[1] = f2bfu(f0.y);
    o.u[2] = f2bfu(f0.z); o.u[3] = f2bfu(f0.w);
    o.u[4] = f2bfu(f1.x); o.u[5] = f2bfu(f1.y);
    o.u[6] = f2bfu(f1.z); o.u[7] = f2bfu(f1.w);
    *(bf16x8*)&dst[idx] = o.v;
  }
}

// ---------------------------------------------------------------------------
// QKV GEMM: BM=256 x BN=192, BK=64. Grid 16x16 = 256 blocks = 1/CU.
// r9: 32x32x16 MFMA (2382 TF ceiling vs 2075, half the MFMA issue count,
// shorter per-phase dependent chains). Waves 4M x 2N; wave tile 64x96 =
// 2x3 tiles of 32x32; acc[2][3] f32x16. Staging & 3-deep A rotation
// unchanged from r8 (same hazard proofs, same XOR swizzle — verified
// conflict-free for the 32x32 fragment read pattern too: 8-lane groups
// cover all 32 banks, 8 accesses/bank = minimum).
// A/B frag: lane l -> row = l&31, k = (l>>5)*8. D: col = lane&31,
// row = (reg&3) + 8*(reg>>2) + 4*(lane>>5)  [guide m74/m101 verified].
// Phases: P1 ds(kh01)+stageA0, MFMA mt0*kh01; P2 ds(kh23)+stageA1,
// MFMA mt1*kh01; P3 MFMA mt0*kh23; P4 stageB, MFMA mt1*kh23, vmcnt(7).
// k ascending per accumulator.
// ---------------------------------------------------------------------------
#define BK 64

__global__ __launch_bounds__(512, 2) void gemm_bt256(
    const __hip_bfloat16* __restrict__ A,
    const __hip_bfloat16* __restrict__ B,
    __hip_bfloat16* __restrict__ C,
    int M, int N, int K, int lda)
{
  __shared__ __align__(16) __hip_bfloat16 As[3][256*BK];  // 96 KiB
  __shared__ __align__(16) __hip_bfloat16 Bs[2][192*BK];  // 48 KiB
  const int tid  = threadIdx.x;
  const int wave = tid >> 6;
  const int lane = tid & 63;
  const int l31  = lane & 31;
  const int hi   = lane >> 5;
  const int m0   = blockIdx.y * 256;
  const int n0   = blockIdx.x * 192;
  const int wm   = (wave >> 1) * 64;   // 4 wave-rows
  const int wn   = (wave & 1) * 96;    // 2 wave-cols

  // A half: 128 rows x 64 cols = 1024 chunks -> 2 loads/thread.
  auto stageAhalf = [&](int buf, int kt, int half) {
    const __hip_bfloat16* src = A + (size_t)(m0 + half*128)*lda + kt*BK;
    __hip_bfloat16* dst = &As[buf][half*128*BK];
#pragma unroll
    for (int i = 0; i < 2; ++i) {
      int c = i*512 + tid;
      int row = c >> 3, sl = c & 7;
      int gs = sl ^ (row & 7);
      async16(&src[(size_t)row*lda + gs*8], &dst[(i*512 + wave*64)*8]);
    }
  };
  // B: 192x64 = 1536 chunks -> 3 loads/thread.
  auto stageB = [&](int buf, int kt) {
    const __hip_bfloat16* src = B + (size_t)n0*K + kt*BK;
    __hip_bfloat16* dst = &Bs[buf][0];
#pragma unroll
    for (int i = 0; i < 3; ++i) {
      int c = i*512 + tid;
      int row = c >> 3, sl = c & 7;
      int gs = sl ^ (row & 7);
      async16(&src[(size_t)row*K + gs*8], &dst[(i*512 + wave*64)*8]);
    }
  };
  // 32x32 fragment reads (row&7 == l31&7 since wm, mt*32 are multiples of 32)
  auto ldA = [&](int buf, int mt, int kh) -> bf16x8 {
    int row = wm + mt*32 + l31;
    return *(const bf16x8*)&As[buf][row*BK + (((kh*2 + hi) ^ (row & 7)) << 3)];
  };
  auto ldB = [&](int buf, int nt, int kh) -> bf16x8 {
    int row = wn + nt*32 + l31;
    return *(const bf16x8*)&Bs[buf][row*BK + (((kh*2 + hi) ^ (row & 7)) << 3)];
  };

  f32x16 acc[2][3] = {};
  const int nt_ = K / BK;

  // prologue: tiles 0,1 fully staged (14 loads); retire tile0 (leave 7).
  stageAhalf(0, 0, 0); stageAhalf(0, 0, 1); stageB(0, 0);
  if (nt_ > 1) {
    stageAhalf(1, 1, 0); stageAhalf(1, 1, 1); stageB(1, 1);
    asm volatile("s_waitcnt vmcnt(7)" ::: "memory");
  } else {
    asm volatile("s_waitcnt vmcnt(0)" ::: "memory");
  }
  __builtin_amdgcn_s_barrier();

#pragma unroll 1
  for (int t = 0; t < nt_; ++t) {
    const int bufA = t % 3;
    const int bufB = t & 1;
    int nextA = bufA + 2; if (nextA >= 3) nextA -= 3;
    const bool pre = (t + 2 < nt_);
    bf16x8 a01[2][2], a23[2][2], b01[3][2], b23[3][2];

    // ---- P1: ds kh0-1 (A 4 + B 6); stage A-half0(t+2); MFMA mt0 x kh0-1 ----
#pragma unroll
    for (int mt = 0; mt < 2; ++mt)
#pragma unroll
      for (int kh = 0; kh < 2; ++kh) a01[mt][kh] = ldA(bufA, mt, kh);
#pragma unroll
    for (int nt = 0; nt < 3; ++nt)
#pragma unroll
      for (int kh = 0; kh < 2; ++kh) b01[nt][kh] = ldB(bufB, nt, kh);
    if (pre) stageAhalf(nextA, t + 2, 0);
    __builtin_amdgcn_s_setprio(1);
#pragma unroll
    for (int kh = 0; kh < 2; ++kh)
#pragma unroll
      for (int nt = 0; nt < 3; ++nt)
        acc[0][nt] = mfma32(a01[0][kh], b01[nt][kh], acc[0][nt]);
    __builtin_amdgcn_s_setprio(0);
    __builtin_amdgcn_s_barrier();

    // ---- P2: ds kh2-3 (A 4 + B 6); stage A-half1(t+2); MFMA mt1 x kh0-1 ----
#pragma unroll
    for (int mt = 0; mt < 2; ++mt)
#pragma unroll
      for (int kh = 0; kh < 2; ++kh) a23[mt][kh] = ldA(bufA, mt, 2 + kh);
#pragma unroll
    for (int nt = 0; nt < 3; ++nt)
#pragma unroll
      for (int kh = 0; kh < 2; ++kh) b23[nt][kh] = ldB(bufB, nt, 2 + kh);
    if (pre) stageAhalf(nextA, t + 2, 1);
    __builtin_amdgcn_s_setprio(1);
#pragma unroll
    for (int kh = 0; kh < 2; ++kh)
#pragma unroll
      for (int nt = 0; nt < 3; ++nt)
        acc[1][nt] = mfma32(a01[1][kh], b01[nt][kh], acc[1][nt]);
    __builtin_amdgcn_s_setprio(0);
    __builtin_amdgcn_s_barrier();

    // ---- P3: MFMA mt0 x kh2-3 ----
    __builtin_amdgcn_s_setprio(1);
#pragma unroll
    for (int kh = 0; kh < 2; ++kh)
#pragma unroll
      for (int nt = 0; nt < 3; ++nt)
        acc[0][nt] = mfma32(a23[0][kh], b23[nt][kh], acc[0][nt]);
    __builtin_amdgcn_s_setprio(0);
    __builtin_amdgcn_s_barrier();

    // ---- P4: stage B(t+2); MFMA mt1 x kh2-3; gate ----
    if (pre) stageB(bufB, t + 2);
    __builtin_amdgcn_s_setprio(1);
#pragma unroll
    for (int kh = 0; kh < 2; ++kh)
#pragma unroll
      for (int nt = 0; nt < 3; ++nt)
        acc[1][nt] = mfma32(a23[1][kh], b23[nt][kh], acc[1][nt]);
    __builtin_amdgcn_s_setprio(0);
    if (pre) asm volatile("s_waitcnt vmcnt(7)" ::: "memory");
    else     asm volatile("s_waitcnt vmcnt(0)" ::: "memory");
    __builtin_amdgcn_s_barrier();
  }

  // D layout (32x32): col = lane&31, row = (reg&3) + 8*(reg>>2) + 4*(lane>>5)
#pragma unroll
  for (int mt = 0; mt < 2; ++mt)
#pragma unroll
    for (int nt = 0; nt < 3; ++nt) {
      int colg = n0 + wn + nt*32 + l31;
#pragma unroll
      for (int r = 0; r < 16; ++r) {
        int rowl = (r & 3) + 8*(r >> 2) + 4*hi;
        int rowg = m0 + wm + mt*32 + rowl;
        C[(size_t)rowg*N + colg] = __float2bfloat16(acc[mt][nt][r]);
      }
    }
}

// ---------------------------------------------------------------------------
// Output GEMM: r0-verified 128x128 BK=32 structure (2 blocks/CU, 512
// balanced blocks) + per-wave dtype self-detect for the epilogue.
// ---------------------------------------------------------------------------
__global__ __launch_bounds__(256, 2) void gemm_out(
    const __hip_bfloat16* __restrict__ A,
    const __hip_bfloat16* __restrict__ B,
    void* __restrict__ C,
    int M, int N, int K, int lda, const void* __restrict__ xorig)
{
  const bool isbf = detect_bf16(xorig);
  __shared__ __align__(16) __hip_bfloat16 As[128*32];
  __shared__ __align__(16) __hip_bfloat16 Bs[128*32];
  const int tid  = threadIdx.x;
  const int wave = tid >> 6;
  const int lane = tid & 63;
  const int qd   = lane >> 4;
  const int ln   = lane & 15;
  const int m0   = blockIdx.y * 128;
  const int n0   = blockIdx.x * 128;
  const int wm   = (wave >> 1) * 64;
  const int wn   = (wave & 1) * 64;

  f32x4 acc[4][4] = {};

  for (int k0 = 0; k0 < K; k0 += 32) {
    __syncthreads();
#pragma unroll
    for (int r = 0; r < 2; ++r) {
      int e   = (r*256 + tid) * 8;
      int row = e >> 5;
      int col = e & 31;
      async16(&A[(size_t)(m0+row)*lda + k0 + col], &As[(size_t)(r*256 + wave*64)*8]);
      async16(&B[(size_t)(n0+row)*K   + k0 + col], &Bs[(size_t)(r*256 + wave*64)*8]);
    }
    __syncthreads();
    bf16x8 af[4], bfr[4];
#pragma unroll
    for (int i = 0; i < 4; ++i)
      af[i] = *(const bf16x8*)&As[(wm + i*16 + ln)*32 + qd*8];
#pragma unroll
    for (int j = 0; j < 4; ++j)
      bfr[j] = *(const bf16x8*)&Bs[(wn + j*16 + ln)*32 + qd*8];
#pragma unroll
    for (int i = 0; i < 4; ++i)
#pragma unroll
      for (int j = 0; j < 4; ++j)
        acc[i][j] = mfma16(af[i], bfr[j], acc[i][j]);
  }
#pragma unroll
  for (int i = 0; i < 4; ++i)
#pragma unroll
    for (int j = 0; j < 4; ++j) {
      int row = m0 + wm + i*16 + qd*4;
      int col = n0 + wn + j*16 + ln;
#pragma unroll
      for (int r = 0; r < 4; ++r) {
        if (isbf) ((__hip_bfloat16*)C)[(size_t)(row + r)*N + col] = __float2bfloat16(acc[i][j][r]);
        else      ((float*)C)[(size_t)(row + r)*N + col] = acc[i][j][r];
      }
    }
}

// ---------------------------------------------------------------------------
// Fused prep (RMSNorm+RoPE+gain on q,k) + transpose_v (disjoint qkv columns).
// ---------------------------------------------------------------------------
__global__ __launch_bounds__(256) void prep_and_tv(
    __hip_bfloat16* __restrict__ qkv,  // [4096][3072]: q | k | v
    const __hip_bfloat16* __restrict__ gain,
    __hip_bfloat16* __restrict__ vt)   // [B][NKV][HDIM][TSEQ]
{
  int blk = blockIdx.x;
  if (blk < 10240) {
    int wid2 = blk * 4 + (threadIdx.x >> 6);  // wave id; 2 rows/wave
    int lane = threadIdx.x & 63;
    int half = lane >> 5;
    int l32  = lane & 31;
    int rowid = wid2 * 2 + half;       // 0 .. 81919
    bool isq = rowid < MROWS*NH;
    int m, h;
    __hip_bfloat16* p;
    if (isq) { m = rowid >> 4; h = rowid & 15; p = qkv + (size_t)m*QKVC + h*HDIM; }
    else     { int w2 = rowid - MROWS*NH; m = w2 >> 2; h = w2 & 3; p = qkv + (size_t)m*QKVC + CDIM + h*HDIM; }

    ushort4 raw = *(const ushort4*)((const unsigned short*)p + 4*l32);
    float e0 = bfbits2f(raw.x), o0 = bfbits2f(raw.y);
    float e1 = bfbits2f(raw.z), o1 = bfbits2f(raw.w);
    float ss = (e0*e0 + o0*o0) + (e1*e1 + o1*o1);
#pragma unroll
    for (int off = 16; off >= 1; off >>= 1) ss += __shfl_xor(ss, off);
    float rms = rsqrtf(ss * (1.0f/128.0f) + 1.1920928955078125e-07f);
    e0 *= rms; o0 *= rms; e1 *= rms; o1 *= rms;

    int j0 = 2*l32;
    float th0 = exp2f(-(float)(2*j0)     * (1.0f/128.0f) * 13.287712379549449f);
    float th1 = exp2f(-(float)(2*j0 + 2) * (1.0f/128.0f) * 13.287712379549449f);
    int t = m & (TSEQ-1);
    float fr0 = (float)t * th0, fr1 = (float)t * th1;
    float c0 = cosf(fr0), s0 = sinf(fr0);
    float c1 = cosf(fr1), s1 = sinf(fr1);
    float re0 = e0*c0 - o0*s0, ro0 = e0*s0 + o0*c0;
    float re1 = e1*c1 - o1*s1, ro1 = e1*s1 + o1*c1;

    if (isq) {
      float g = bfbits2f(*(const unsigned short*)&gain[h]) * 0.08838834764831845f;
      re0 *= g; ro0 *= g; re1 *= g; ro1 *= g;
    }
    ushort4 outv;
    outv.x = f2bfu(re0); outv.y = f2bfu(ro0);
    outv.z = f2bfu(re1); outv.w = f2bfu(ro1);
    *(ushort4*)((unsigned short*)p + 4*l32) = outv;
  } else {
    __shared__ __hip_bfloat16 tile[32][34];
    int bx = blk - 10240;
    int tx = threadIdx.x & 31;
    int ty = threadIdx.x >> 5;
    int r0 = (bx & 127) * 32;
    int c0 = (bx >> 7) * 32;
#pragma unroll
    for (int i = 0; i < 4; ++i)
      tile[ty + i*8][tx] = qkv[(size_t)(r0 + ty + i*8)*QKVC + (CDIM + KVC) + c0 + tx];
    __syncthreads();
    int b = r0 >> 11;
    int t = r0 & (TSEQ-1);
    int hk = c0 >> 7;
    int d0 = c0 & (HDIM-1);
#pragma unroll
    for (int i = 0; i < 4; ++i) {
      int d = d0 + ty + i*8;
      vt[((size_t)((b*NKV + hk)*HDIM + d))*TSEQ + t + tx] = tile[tx][ty + i*8];
    }
  }
}

// Flash attention v9: balanced pairs {p,31-p}, 4 waves, swapped-operand
// dataflow (verified r4-r8).
__global__ __launch_bounds__(256, 2) void attn_kernel(
    const __hip_bfloat16* __restrict__ qkv, // [B][T][3072] (read-only here)
    const __hip_bfloat16* __restrict__ vt,  // [B][NKV][HD][T]
    __hip_bfloat16* __restrict__ out)       // [B][T][2048] attn output
{
  const int tid  = threadIdx.x;
  const int wave = tid >> 6;   // 0..3
  const int lane = tid & 63;
  const int qd = lane >> 4, ln = lane & 15;
  const int p  = blockIdx.x;     // pair index 0..15 -> q-tiles {p, 31-p}
  const int h  = blockIdx.y;
  const int b  = blockIdx.z;
  const int hk = h >> 2;

  const __hip_bfloat16* K = qkv + (size_t)(b*TSEQ)*QKVC + CDIM + hk*HDIM;
  const __hip_bfloat16* V = vt + ((size_t)(b*NKV + hk)*HDIM)*TSEQ;

  __shared__ __align__(16) __hip_bfloat16 Ks[64*128];  // [t][d], swz128
  __shared__ __align__(16) __hip_bfloat16 Vs[128*64];  // [d][t], swz64
  __shared__ __align__(16) __hip_bfloat16 Pb[64*64];   // P^T as [q][kv], swz64
  __shared__ float Lb[4][64];                          // per-wave l partials

  auto issueK = [&](int t0) {
#pragma unroll
    for (int i = 0; i < 4; ++i) {
      int c = i*256 + tid;             // chunk; 16 chunks/row
      int row = c >> 4, cc = c & 15;
      int gcc = cc ^ (row & 15);
      async16(&K[(size_t)(t0 + row)*QKVC + gcc*8], &Ks[(i*256 + wave*64)*8]);
    }
  };
  auto issueV = [&](int t0) {
#pragma unroll
    for (int i = 0; i < 4; ++i) {
      int c = i*256 + tid;             // chunk; 8 chunks/row
      int row = c >> 3, cc = c & 7;
      int gcc = cc ^ (row & 7);
      async16(&V[(size_t)row*TSEQ + t0 + gcc*8], &Vs[(i*256 + wave*64)*8]);
    }
  };

#pragma unroll 1
  for (int seg = 0; seg < 2; ++seg) {
    const int qt = seg ? (31 - p) : p;
    const int q0 = qt * 64;

    // Q as B-operand fragments (col q = qsub*16+ln, k = kc*32+qd*8+e)
    bf16x8 qfr[4][4];
#pragma unroll
    for (int qsub = 0; qsub < 4; ++qsub)
#pragma unroll
      for (int kc = 0; kc < 4; ++kc)
        qfr[qsub][kc] = *(const bf16x8*)&qkv[((size_t)(b*TSEQ + q0 + qsub*16 + ln))*QKVC + h*HDIM + kc*32 + qd*8];

    // O^T accumulator: o[half][qsub] holds O^T[d = wave*32+half*16+qd*4+r][q = qsub*16+ln]
    f32x4 o[2][4] = {};
    float lacc[4] = {0.f, 0.f, 0.f, 0.f};

    __syncthreads();          // Ks free (prev segment epilogue readback done)
    issueK(0);
    __syncthreads();          // drain K[0]

#pragma unroll 1
    for (int kt = 0; kt <= qt; ++kt) {
      const int t0 = kt * 64;
      issueV(t0);             // Vs free since prev iter-end barrier

      // ---- QK^T swapped: S^T[kv][q], wave owns kv-rows wave*16..+15 ----
      f32x4 sc[4] = {};
#pragma unroll
      for (int kc = 0; kc < 4; ++kc) {
        bf16x8 kfa = *(const bf16x8*)&Ks[swz128(wave*16 + ln, kc*32 + qd*8)];
#pragma unroll
        for (int qsub = 0; qsub < 4; ++qsub)
          sc[qsub] = mfma16(kfa, qfr[qsub][kc], sc[qsub]);
      }
      if (kt == qt) {  // diagonal: causal mask (D: row=kv=qd*4+r, col=q=ln)
#pragma unroll
        for (int qsub = 0; qsub < 4; ++qsub)
#pragma unroll
          for (int r = 0; r < 4; ++r) {
            int kv = t0 + wave*16 + qd*4 + r;
            int q  = q0 + qsub*16 + ln;
            if (kv > q) sc[qsub][r] = -1.0e30f;
          }
      }
      // fixed-offset softmax: p = exp(s), defer l reduction
#pragma unroll
      for (int qsub = 0; qsub < 4; ++qsub) {
#pragma unroll
        for (int r = 0; r < 4; ++r)
          sc[qsub][r] = __expf(sc[qsub][r]);
        lacc[qsub] += (sc[qsub][0] + sc[qsub][1]) + (sc[qsub][2] + sc[qsub][3]);
      }

      // write P^T to Pb[q][kv] (8B packed, swz64; kv = wave*16+qd*4+r)
#pragma unroll
      for (int qsub = 0; qsub < 4; ++qsub) {
        ushort4 pk;
        pk.x = f2bfu(sc[qsub][0]); pk.y = f2bfu(sc[qsub][1]);
        pk.z = f2bfu(sc[qsub][2]); pk.w = f2bfu(sc[qsub][3]);
        *(ushort4*)&Pb[swz64(qsub*16 + ln, wave*16 + qd*4)] = pk;
      }

      __syncthreads();        // P visible; V[kt] drained; Ks consumed by all
      if (kt < qt) issueK(t0 + 64);   // overlaps PV

      // ---- PV d-split: O^T[d][q] += V^T[d][kv] * P^T[kv][q] ----
      __builtin_amdgcn_s_setprio(1);
#pragma unroll
      for (int kc2 = 0; kc2 < 2; ++kc2) {
        bf16x8 pfb[4];
#pragma unroll
        for (int qsub = 0; qsub < 4; ++qsub)
          pfb[qsub] = *(const bf16x8*)&Pb[swz64(qsub*16 + ln, kc2*32 + qd*8)];
#pragma unroll
        for (int half = 0; half < 2; ++half) {
          bf16x8 vfa = *(const bf16x8*)&Vs[swz64(wave*32 + half*16 + ln, kc2*32 + qd*8)];
#pragma unroll
          for (int qsub = 0; qsub < 4; ++qsub)
            o[half][qsub] = mfma16(vfa, pfb[qsub], o[half][qsub]);
        }
      }
      __builtin_amdgcn_s_setprio(0);
      __syncthreads();        // drain K[kt+1]; Vs & Pb free
    }

    // l: reduce across qd groups (kv within wave), then across waves via LDS
#pragma unroll
    for (int qsub = 0; qsub < 4; ++qsub) {
      lacc[qsub] += __shfl_xor(lacc[qsub], 16);
      lacc[qsub] += __shfl_xor(lacc[qsub], 32);
    }
    if (qd == 0) {
#pragma unroll
      for (int qsub = 0; qsub < 4; ++qsub)
        Lb[wave][qsub*16 + ln] = lacc[qsub];
    }
    __syncthreads();
    float inv[4];
#pragma unroll
    for (int qsub = 0; qsub < 4; ++qsub) {
      int q = qsub*16 + ln;
      inv[qsub] = 1.0f / (((Lb[0][q] + Lb[1][q]) + (Lb[2][q] + Lb[3][q])));
    }

    // epilogue: Obuf = Ks reuse, [q 64][d 128] swz128; wave writes its d-cols
#pragma unroll
    for (int half = 0; half < 2; ++half)
#pragma unroll
      for (int qsub = 0; qsub < 4; ++qsub) {
        ushort4 pk;
        pk.x = f2bfu(o[half][qsub][0] * inv[qsub]);
        pk.y = f2bfu(o[half][qsub][1] * inv[qsub]);
        pk.z = f2bfu(o[half][qsub][2] * inv[qsub]);
        pk.w = f2bfu(o[half][qsub][3] * inv[qsub]);
        *(ushort4*)&Ks[swz128(qsub*16 + ln, wave*32 + half*16 + qd*4)] = pk;
      }
    __syncthreads();          // writes visible before readback
#pragma unroll
    for (int pass = 0; pass < 4; ++pass) {
      int row = wave*16 + pass*4 + qd;
      bf16x8 val = *(const bf16x8*)&Ks[swz128(row, ln*8)];
      int q = q0 + row;
      *(bf16x8*)&out[((size_t)(b*TSEQ + q))*CDIM + h*HDIM + ln*8] = val;
    }
  }
}

extern "C" void kernel_launch(void* const* d_in, const int* in_sizes, int n_in,
                              void* d_out, int out_size, void* d_ws, size_t ws_size,
                              hipStream_t stream) {
  char* ws = (char*)d_ws;
  size_t off = 0;
  auto alloc = [&](size_t bytes) { char* p = ws + off; off += (bytes + 255) & ~(size_t)255; return p; };

  __hip_bfloat16* xb   = (__hip_bfloat16*)alloc((size_t)MROWS*CDIM*2);   // 16.8 MB (x, then attn out)
  __hip_bfloat16* wqkv = (__hip_bfloat16*)alloc((size_t)QKVC*CDIM*2);    // 12.6 MB
  __hip_bfloat16* wob  = (__hip_bfloat16*)alloc((size_t)CDIM*CDIM*2);    //  8.4 MB
  __hip_bfloat16* gb   = (__hip_bfloat16*)alloc(256);
  __hip_bfloat16* qkv  = (__hip_bfloat16*)alloc((size_t)MROWS*QKVC*2);   // 25.2 MB
  __hip_bfloat16* vt   = (__hip_bfloat16*)alloc((size_t)MROWS*KVC*2);    //  4.2 MB

  // 1) canonize (per-wave dtype self-detect; no canary kernel)
  canonize_all<<<9217, 256, 0, stream>>>(
      d_in[0], d_in[1], d_in[2], d_in[3], d_in[4], d_in[5],
      xb, wqkv, wob, gb);

  // 2) fused QKV projection: BM=256 x BN=192 -> 256 blocks = 1/CU
  gemm_bt256<<<dim3(QKVC/192, MROWS/256), 512, 0, stream>>>(
      xb, wqkv, qkv, MROWS, QKVC, CDIM, CDIM);

  // 3) fused prep(q,k) + transpose_v: 10240 + 2048 blocks
  prep_and_tv<<<12288, 256, 0, stream>>>(qkv, gb, vt);

  // 4) attention: balanced pairs {p, 31-p}, swapped-operand
  attn_kernel<<<dim3(16, NH, BATCH), 256, 0, stream>>>(qkv, vt, xb);

  // 5) output projection: r0-verified 128x128, 512 blocks (2/CU)
  gemm_out<<<dim3(CDIM/128, MROWS/128), 256, 0, stream>>>(
      xb, wob, d_out, MROWS, CDIM, CDIM, CDIM, d_in[0]);
}